// Round 7
// baseline (10886.198 us; speedup 1.0000x reference)
//
#include <hip/hip_runtime.h>

#define B_ 32
#define NP 196
#define PD 768
#define DM 512
#define NC 1000
#define MAT (NP*NP)

// ---------------- patchify + LN + pos ----------------
__global__ __launch_bounds__(256) void k_patchify(
    const float* __restrict__ img, const float* __restrict__ g,
    const float* __restrict__ be, const float* __restrict__ pos,
    float* __restrict__ x) {
  int bn = blockIdx.x;
  int b = bn / NP, n = bn % NP;
  int gh = n / 14, gw = n % 14;
  int t = threadIdx.x;
  float vals[3]; float s = 0.f, ss = 0.f;
  #pragma unroll
  for (int k = 0; k < 3; ++k) {
    int e = t + (k << 8);
    int inner = e & 255;
    int ph = inner >> 4, pw = inner & 15;
    float v = img[((b*3 + k)*224 + gh*16 + ph)*224 + gw*16 + pw];
    vals[k] = v; s += v; ss += v*v;
  }
  __shared__ float rb[8];
  for (int o = 32; o; o >>= 1) { s += __shfl_down(s,o); ss += __shfl_down(ss,o); }
  if ((t & 63) == 0) { rb[t>>6] = s; rb[4+(t>>6)] = ss; }
  __syncthreads();
  float S = rb[0]+rb[1]+rb[2]+rb[3], SS = rb[4]+rb[5]+rb[6]+rb[7];
  float mu = S * (1.f/768.f);
  float var = SS * (1.f/768.f) - mu*mu;
  float inv = rsqrtf(var + 1e-5f);
  #pragma unroll
  for (int k = 0; k < 3; ++k) {
    int e = t + (k << 8);
    x[(size_t)bn*PD + e] = (vals[k]-mu)*inv*g[e] + be[e] + pos[n*PD + e];
  }
}

// ---------------- merged Q/V GEMM: M=6272 K=768 N=512 (64x64 tile) ----------------
__global__ __launch_bounds__(256) void k_qv(
    const float* __restrict__ A,
    const float* __restrict__ wq, const float* __restrict__ bq,
    const float* __restrict__ wv, const float* __restrict__ bv,
    float* __restrict__ qo, float* __restrict__ vo) {
  const float* W    = blockIdx.z ? wv : wq;
  const float* bias = blockIdx.z ? bv : bq;
  float* out        = blockIdx.z ? vo : qo;
  __shared__ __align__(16) float As[16][68];
  __shared__ __align__(16) float Bs[16][64];
  int n0 = blockIdx.x * 64, m0 = blockIdx.y * 64;
  int t = threadIdx.x, tx = t & 15, ty = t >> 4;
  int alr = t >> 2, alc = (t & 3) << 2;
  int blr = t >> 4, blc = (t & 15) << 2;
  float acc[4][4] = {};
  for (int k0 = 0; k0 < 768; k0 += 16) {
    float4 av = *reinterpret_cast<const float4*>(&A[(size_t)(m0+alr)*768 + k0 + alc]);
    float4 bvv = *reinterpret_cast<const float4*>(&W[(size_t)(k0+blr)*512 + n0 + blc]);
    As[alc+0][alr] = av.x; As[alc+1][alr] = av.y;
    As[alc+2][alr] = av.z; As[alc+3][alr] = av.w;
    *reinterpret_cast<float4*>(&Bs[blr][blc]) = bvv;
    __syncthreads();
    #pragma unroll
    for (int kt = 0; kt < 16; ++kt) {
      float a4[4], b4[4];
      *reinterpret_cast<float4*>(a4) = *reinterpret_cast<const float4*>(&As[kt][ty<<2]);
      *reinterpret_cast<float4*>(b4) = *reinterpret_cast<const float4*>(&Bs[kt][tx<<2]);
      #pragma unroll
      for (int i = 0; i < 4; ++i)
        #pragma unroll
        for (int j = 0; j < 4; ++j) acc[i][j] += a4[i]*b4[j];
    }
    __syncthreads();
  }
  float4 bb = *reinterpret_cast<const float4*>(&bias[n0 + (tx<<2)]);
  float bb4[4] = {bb.x, bb.y, bb.z, bb.w};
  #pragma unroll
  for (int i = 0; i < 4; ++i) {
    float4 o;
    o.x = acc[i][0]+bb4[0]; o.y = acc[i][1]+bb4[1];
    o.z = acc[i][2]+bb4[2]; o.w = acc[i][3]+bb4[3];
    *reinterpret_cast<float4*>(&out[(size_t)(m0+(ty<<2)+i)*512 + n0 + (tx<<2)]) = o;
  }
}

// ---------------- merged row LayerNorm for q (scale 1) and v (scale 1/196) ----------------
__global__ __launch_bounds__(256) void k_ln2(
    float* __restrict__ q, float* __restrict__ v,
    const float* __restrict__ gq, const float* __restrict__ bq,
    const float* __restrict__ gv, const float* __restrict__ bv) {
  int r = blockIdx.x; bool hv = (r >= B_*NP); if (hv) r -= B_*NP;
  float* X = hv ? v : q;
  const float* g  = hv ? gv : gq;
  const float* be = hv ? bv : bq;
  float scale = hv ? (1.f/196.f) : 1.f;
  int t = threadIdx.x;
  float v0 = X[(size_t)r*512 + t], v1 = X[(size_t)r*512 + 256 + t];
  float s = v0+v1, ss = v0*v0+v1*v1;
  __shared__ float rb[8];
  for (int o = 32; o; o >>= 1) { s += __shfl_down(s,o); ss += __shfl_down(ss,o); }
  if ((t&63)==0) { rb[t>>6]=s; rb[4+(t>>6)]=ss; }
  __syncthreads();
  float S = rb[0]+rb[1]+rb[2]+rb[3], SS = rb[4]+rb[5]+rb[6]+rb[7];
  float mu = S*(1.f/512.f), var = SS*(1.f/512.f)-mu*mu;
  float inv = rsqrtf(var+1e-5f);
  X[(size_t)r*512+t]     = ((v0-mu)*inv*g[t]+be[t])*scale;
  X[(size_t)r*512+256+t] = ((v1-mu)*inv*g[t+256]+be[t+256])*scale;
}

// ---------------- merged Gram: z<32: A=2VV^T+I ; z>=32: p=-2QV^T+1/196 ----------------
__global__ __launch_bounds__(256) void k_gram(
    const float* __restrict__ q, const float* __restrict__ v,
    float* __restrict__ Ao, float* __restrict__ po) {
  int zz = blockIdx.z; int b = zz & 31; bool hp = (zz >= 32);
  float alpha  = hp ? -2.f : 2.f;
  float diagAdd = hp ? 0.f : 1.f;
  float cAdd   = hp ? (1.f/196.f) : 0.f;
  const float* Xb = (hp ? q : v) + (size_t)b*NP*512;
  const float* Yb = v + (size_t)b*NP*512;
  float* out = (hp ? po : Ao) + (size_t)b*MAT;
  int c0 = blockIdx.x * 64, r0 = blockIdx.y * 64;
  __shared__ __align__(16) float Xs[16][68];
  __shared__ __align__(16) float Ys[16][68];
  int t = threadIdx.x, tx = t & 15, ty = t >> 4;
  int lr = t >> 2, lc4 = (t & 3) << 2;
  float acc[4][4] = {};
  int xr = min(r0 + lr, NP-1), yr = min(c0 + lr, NP-1);
  for (int k0 = 0; k0 < 512; k0 += 16) {
    float4 xv = *reinterpret_cast<const float4*>(&Xb[(size_t)xr*512 + k0 + lc4]);
    float4 yv = *reinterpret_cast<const float4*>(&Yb[(size_t)yr*512 + k0 + lc4]);
    Xs[lc4+0][lr] = xv.x; Xs[lc4+1][lr] = xv.y;
    Xs[lc4+2][lr] = xv.z; Xs[lc4+3][lr] = xv.w;
    Ys[lc4+0][lr] = yv.x; Ys[lc4+1][lr] = yv.y;
    Ys[lc4+2][lr] = yv.z; Ys[lc4+3][lr] = yv.w;
    __syncthreads();
    #pragma unroll
    for (int kt = 0; kt < 16; ++kt) {
      float a4[4], b4[4];
      *reinterpret_cast<float4*>(a4) = *reinterpret_cast<const float4*>(&Xs[kt][ty<<2]);
      *reinterpret_cast<float4*>(b4) = *reinterpret_cast<const float4*>(&Ys[kt][tx<<2]);
      #pragma unroll
      for (int i = 0; i < 4; ++i)
        #pragma unroll
        for (int j = 0; j < 4; ++j) acc[i][j] += a4[i]*b4[j];
    }
    __syncthreads();
  }
  #pragma unroll
  for (int i = 0; i < 4; ++i) {
    int r = r0 + (ty<<2) + i; if (r >= NP) continue;
    #pragma unroll
    for (int j = 0; j < 4; ++j) {
      int c = c0 + (tx<<2) + j; if (c >= NP) continue;
      out[(size_t)r*NP + c] = alpha*acc[i][j] + cAdd + (r==c ? diagAdd : 0.f);
    }
  }
}

// ---------------- NS init: ninf bound, X0 = c*I, Y0 = c*A (Y tracks A@X) ----------------
__global__ __launch_bounds__(256) void k_nsinit2(
    const float* __restrict__ A, float* __restrict__ X, float* __restrict__ Y) {
  int b = blockIdx.x, t = threadIdx.x;
  const float* Ab = A + (size_t)b*MAT;
  __shared__ float sm[256];
  float lm = 0.f;
  if (t < NP) {
    float s = 0.f;
    for (int j = 0; j < NP; ++j) {
      float v = Ab[t*NP + j];
      if (j == t) v -= 1.f;
      s += fabsf(v);
    }
    lm = s;
  }
  sm[t] = lm; __syncthreads();
  for (int o = 128; o; o >>= 1) { if (t < o) sm[t] = fmaxf(sm[t], sm[t+o]); __syncthreads(); }
  float cc = 2.f / (2.f + sm[0]);
  float* Xb = X + (size_t)b*MAT;
  float* Yb = Y + (size_t)b*MAT;
  for (int idx = t; idx < MAT; idx += 256) {
    Xb[idx] = (idx % (NP+1) == 0) ? cc : 0.f;
    Yb[idx] = cc * Ab[idx];
  }
}

// ---------------- NS iter (X,Y independent halves): z<32: Xn=2X-X@Y ; z>=32: Yn=2Y-Y@Y ----------------
__global__ __launch_bounds__(256) void k_ns(
    const float* __restrict__ X, const float* __restrict__ Y,
    float* __restrict__ Xn, float* __restrict__ Yn) {
  int zz = blockIdx.z; int b = zz & 31; bool hy = (zz >= 32);
  const float* Lb = (hy ? Y : X) + (size_t)b*MAT;
  const float* Rb = Y + (size_t)b*MAT;
  float* Ob = (hy ? Yn : Xn) + (size_t)b*MAT;
  int c0 = blockIdx.x * 64, r0 = blockIdx.y * 64;
  __shared__ __align__(16) float Ls[16][68];
  __shared__ __align__(16) float Rs[16][64];
  int t = threadIdx.x, tx = t & 15, ty = t >> 4;
  int alr = t >> 2, alc = (t & 3) << 2;
  int blr = t >> 4, blc = (t & 15) << 2;
  float acc[4][4] = {};
  int lrow = min(r0 + alr, NP-1);
  for (int k0 = 0; k0 < NP; k0 += 16) {
    float4 lv = {0.f,0.f,0.f,0.f};
    if (k0 + alc < NP) lv = *reinterpret_cast<const float4*>(&Lb[(size_t)lrow*NP + k0 + alc]);
    float4 rv = {0.f,0.f,0.f,0.f};
    if (k0 + blr < NP) rv = *reinterpret_cast<const float4*>(&Rb[(size_t)(k0+blr)*NP + c0 + blc]);
    Ls[alc+0][alr] = lv.x; Ls[alc+1][alr] = lv.y;
    Ls[alc+2][alr] = lv.z; Ls[alc+3][alr] = lv.w;
    *reinterpret_cast<float4*>(&Rs[blr][blc]) = rv;
    __syncthreads();
    #pragma unroll
    for (int kt = 0; kt < 16; ++kt) {
      float a4[4], b4[4];
      *reinterpret_cast<float4*>(a4) = *reinterpret_cast<const float4*>(&Ls[kt][ty<<2]);
      *reinterpret_cast<float4*>(b4) = *reinterpret_cast<const float4*>(&Rs[kt][tx<<2]);
      #pragma unroll
      for (int i = 0; i < 4; ++i)
        #pragma unroll
        for (int j = 0; j < 4; ++j) acc[i][j] += a4[i]*b4[j];
    }
    __syncthreads();
  }
  #pragma unroll
  for (int i = 0; i < 4; ++i) {
    int r = r0 + (ty<<2) + i; if (r >= NP) continue;
    #pragma unroll
    for (int j = 0; j < 4; ++j) {
      int c = c0 + (tx<<2) + j; if (c >= NP) continue;
      Ob[(size_t)r*NP + c] = 2.f*Lb[(size_t)r*NP + c] - acc[i][j];
    }
  }
}

// ---------------- fused 50-iter ADMM v6: v4 layout + pair-pipelined Minv loads ----
// 800 blocks (25 tiles x 8 tokens x 32 batches), 256 thr = 8 ty x 32 tx,
// launch_bounds(256,3) (VGPR cap ~170; NOT (256,4): caps VGPR at 64 -> spills, r5).
// Lane tx<28 owns m in {tx+28k} (coalesced Minv loads). ty owns j rows
// [24ty,24ty+24); tail rows 192..195 as one pair each for ty6/ty7 (wave 3).
// j-loop in PAIRS with double-buffered registers: prefetch pair p+1 while
// FMAing pair p (112 FMAs/pair wall >> L2 latency) -> hides v4's load stall.
// Same FP summation order as v4. LDS 32 KB, stride-1 lane access, 0 conflicts.
#define LOADPAIR(ptr, v0, v1)                         \
  do {                                                \
    const float* _bp = (ptr);                         \
    _Pragma("unroll")                                 \
    for (int k = 0; k < 7; ++k) {                     \
      v0[k] = _bp[28*k];                              \
      v1[k] = _bp[NP + 28*k];                         \
    }                                                 \
  } while (0)

#define FMAPAIR(v0, v1, jj)                                      \
  do {                                                           \
    float2 rr[8];                                                \
    _Pragma("unroll")                                            \
    for (int n = 0; n < 8; ++n)                                  \
      rr[n] = *reinterpret_cast<const float2*>(&rsT[n][jj]);     \
    _Pragma("unroll")                                            \
    for (int n = 0; n < 8; ++n) {                                \
      _Pragma("unroll")                                          \
      for (int k = 0; k < 7; ++k)                                \
        acc[n][k] = fmaf(v0[k], rr[n].x, acc[n][k]);             \
      _Pragma("unroll")                                          \
      for (int k = 0; k < 7; ++k)                                \
        acc[n][k] = fmaf(v1[k], rr[n].y, acc[n][k]);             \
    }                                                            \
  } while (0)

__global__ __launch_bounds__(256, 3) void k_admm6(
    const float* __restrict__ Minv, const float* __restrict__ P,
    float* __restrict__ w) {
  int bid = blockIdx.x;
  int b = bid & 31;
  int tile = bid >> 5;
  int n0 = tile * 8;
  int t = threadIdx.x;
  int tx = t & 31, ty = t >> 5, wv = t >> 6;
  bool act = (tx < 28);
  int m0 = tx;

  __shared__ __align__(16) float rsT[8][200];   // rhs, [token][m]
  __shared__ float rp[4][8][200];               // per-wave j-partials

  const float* Mb = Minv + (size_t)b * MAT;
  const float* Pb = P + (size_t)b * MAT;

  int jstart = 24 * ty;
  bool tail = (ty >= 6);                 // wave-3-uniform
  int jtail = 192 + 2 * (ty - 6);
  const float* tbase = Mb + (size_t)(tail ? jtail : 0) * NP + m0;

  float z[7], u[7], pr[7];
  #pragma unroll
  for (int k = 0; k < 7; ++k) { z[k] = 0.f; u[k] = 0.f; pr[k] = 0.f; }

  int ng = min(n0 + ty, NP - 1);         // pad dups token 195 (masked later)
  if (act) {
    const float* prow = Pb + (size_t)ng * NP + m0;
    #pragma unroll
    for (int k = 0; k < 7; ++k) pr[k] = prow[28*k];
    #pragma unroll
    for (int k = 0; k < 7; ++k) rsT[ty][m0 + 28*k] = -pr[k];  // rhs0 = -p
  }
  __syncthreads();

  for (int it = 0; it < 50; ++it) {
    float acc[8][7];
    if (act) {
      #pragma unroll
      for (int n = 0; n < 8; ++n)
        #pragma unroll
        for (int k = 0; k < 7; ++k) acc[n][k] = 0.f;
      const float* base = Mb + (size_t)jstart * NP + m0;
      float A0[7], A1[7], B0[7], B1[7];
      LOADPAIR(base, A0, A1);            // pair 0 -> A
      #pragma unroll
      for (int p = 0; p < 12; ++p) {
        int j = jstart + 2 * p;
        if ((p & 1) == 0) {
          if (p < 11) LOADPAIR(base + (size_t)(2*p+2)*NP, B0, B1);
          FMAPAIR(A0, A1, j);
        } else {
          if (p < 11) {
            LOADPAIR(base + (size_t)(2*p+2)*NP, A0, A1);
          } else if (tail) {
            LOADPAIR(tbase, A0, A1);     // prefetch tail into freed A
          }
          FMAPAIR(B0, B1, j);
        }
      }
      if (tail) FMAPAIR(A0, A1, jtail);
      // combine the two half-wave j-ranges (result valid in both halves)
      #pragma unroll
      for (int n = 0; n < 8; ++n)
        #pragma unroll
        for (int k = 0; k < 7; ++k)
          acc[n][k] += __shfl_xor(acc[n][k], 32, 64);
      if ((t & 63) < 32) {
        #pragma unroll
        for (int n = 0; n < 8; ++n)
          #pragma unroll
          for (int k = 0; k < 7; ++k)
            rp[wv][n][m0 + 28*k] = acc[n][k];
      }
    }
    __syncthreads();
    if (act) {
      #pragma unroll
      for (int k = 0; k < 7; ++k) {
        int m = m0 + 28*k;
        float x = rp[0][ty][m] + rp[1][ty][m] + rp[2][ty][m] + rp[3][ty][m];
        float xpu = x + u[k];
        float zz = fminf(fmaxf(xpu, 0.f), 1.f);
        u[k] = xpu - zz;
        z[k] = zz;
        rsT[ty][m] = zz - u[k] - pr[k];
      }
    }
    __syncthreads();
  }

  // coeffs = z / (sum z + 1e-10); w[b][m] += mean_n coeffs  (z>=0 after clip)
  float s = 0.f;
  #pragma unroll
  for (int k = 0; k < 7; ++k) s += z[k];
  #pragma unroll
  for (int o = 16; o; o >>= 1) s += __shfl_xor(s, o, 64);
  float inv = 1.f / (s + 1e-10f);
  if (n0 + ty >= NP) inv = 0.f;   // mask pad tokens
  if (act) {
    #pragma unroll
    for (int k = 0; k < 7; ++k)
      atomicAdd(&w[b*NP + m0 + 28*k], z[k] * inv * (1.f/196.f));
  }
}

// ---------------- fused pooled + LN + head + softmax ----------------
__global__ __launch_bounds__(256) void k_finish(
    const float* __restrict__ w, const float* __restrict__ V,
    const float* __restrict__ g, const float* __restrict__ be,
    const float* __restrict__ Wm, const float* __restrict__ bm,
    float* __restrict__ out) {
  int b = blockIdx.x, t = threadIdx.x;
  __shared__ float ws_[NP];
  __shared__ float pl[512];
  __shared__ float rb[8];
  if (t < NP) ws_[t] = w[b*NP + t];
  __syncthreads();
  const float* Vb = V + (size_t)b*NP*512;
  float a0 = 0.f, a1 = 0.f;
  #pragma unroll 4
  for (int m = 0; m < NP; ++m) {
    float wm = ws_[m];
    a0 = fmaf(wm, Vb[(size_t)m*512 + t], a0);
    a1 = fmaf(wm, Vb[(size_t)m*512 + 256 + t], a1);
  }
  float s = a0+a1, ss = a0*a0+a1*a1;
  for (int o = 32; o; o >>= 1) { s += __shfl_down(s,o); ss += __shfl_down(ss,o); }
  if ((t&63)==0) { rb[t>>6]=s; rb[4+(t>>6)]=ss; }
  __syncthreads();
  float S = rb[0]+rb[1]+rb[2]+rb[3], SS = rb[4]+rb[5]+rb[6]+rb[7];
  float mu = S*(1.f/512.f), var = SS*(1.f/512.f)-mu*mu, inv = rsqrtf(var+1e-5f);
  pl[t]     = (a0-mu)*inv*g[t] + be[t];
  pl[t+256] = (a1-mu)*inv*g[t+256] + be[t+256];
  __syncthreads();
  float lg[4];
  #pragma unroll
  for (int qq = 0; qq < 4; ++qq) {
    int c = t + (qq<<8);
    float a = -1e30f;
    if (c < NC) {
      a = bm[c];
      #pragma unroll 8
      for (int k = 0; k < 512; ++k) a += pl[k]*Wm[(size_t)k*NC + c];
    }
    lg[qq] = a;
  }
  float mx = fmaxf(fmaxf(lg[0],lg[1]), fmaxf(lg[2],lg[3]));
  for (int o = 32; o; o >>= 1) mx = fmaxf(mx, __shfl_down(mx,o));
  __syncthreads();
  if ((t&63)==0) rb[t>>6] = mx;
  __syncthreads();
  float MX = fmaxf(fmaxf(rb[0],rb[1]), fmaxf(rb[2],rb[3]));
  float es = 0.f, ev[4];
  #pragma unroll
  for (int qq = 0; qq < 4; ++qq) {
    int c = t + (qq<<8);
    ev[qq] = (c < NC) ? __expf(lg[qq]-MX) : 0.f;
    es += ev[qq];
  }
  for (int o = 32; o; o >>= 1) es += __shfl_down(es,o);
  __syncthreads();
  if ((t&63)==0) rb[4+(t>>6)] = es;
  __syncthreads();
  float SUM = rb[4]+rb[5]+rb[6]+rb[7];
  float rinv = 1.f/SUM;
  #pragma unroll
  for (int qq = 0; qq < 4; ++qq) {
    int c = t + (qq<<8);
    if (c < NC) out[(size_t)b*NC + c] = ev[qq]*rinv;
  }
}

extern "C" void kernel_launch(void* const* d_in, const int* in_sizes, int n_in,
                              void* d_out, int out_size, void* d_ws, size_t ws_size,
                              hipStream_t stream) {
  const float* img = (const float*)d_in[0];
  const float* lpg = (const float*)d_in[1];
  const float* lpb = (const float*)d_in[2];
  const float* wqw = (const float*)d_in[3];
  const float* wqb = (const float*)d_in[4];
  const float* lqg = (const float*)d_in[5];
  const float* lqb = (const float*)d_in[6];
  const float* wvw = (const float*)d_in[7];
  const float* wvb = (const float*)d_in[8];
  const float* lvg = (const float*)d_in[9];
  const float* lvb = (const float*)d_in[10];
  const float* pos = (const float*)d_in[11];
  const float* mlg = (const float*)d_in[12];
  const float* mlb = (const float*)d_in[13];
  const float* mw  = (const float*)d_in[14];
  const float* mb  = (const float*)d_in[15];
  float* outp = (float*)d_out;

  float* ws = (float*)d_ws;
  size_t off = 0;
  float* x  = ws + off;      off += (size_t)B_*NP*PD;
  float* q  = ws + off;      off += (size_t)B_*NP*DM;
  float* v  = ws + off;      off += (size_t)B_*NP*DM;
  size_t matp = (size_t)B_*MAT + 256;  // +tail pad for benign overrun reads
  float* A  = ws + off;      off += matp;   // doubles as Yb after nsinit consumes it
  float* p  = ws + off;      off += matp;
  float* Xa = ws + off;      off += matp;
  float* Xb = ws + off;      off += matp;
  float* Ya = ws + off;      off += matp;
  float* Yb = A;                            // alias: A dead after k_nsinit2
  float* w  = ws + off;      off += (size_t)B_*NP;
  if (ws_size < off * sizeof(float)) return;  // workspace too small -> fail loudly

  k_patchify<<<dim3(B_*NP), 256, 0, stream>>>(img, lpg, lpb, pos, x);
  k_qv<<<dim3(8, 98, 2), 256, 0, stream>>>(x, wqw, wqb, wvw, wvb, q, v);
  k_ln2<<<dim3(2*B_*NP), 256, 0, stream>>>(q, v, lqg, lqb, lvg, lvb);
  // A = 2VV^T + I ; p = -2QV^T + 1/196   (one dispatch)
  k_gram<<<dim3(4,4,64), 256, 0, stream>>>(q, v, A, p);
  // Newton-Schulz with Y=A@X invariant: X<-2X-XY, Y<-2Y-YY (independent).
  k_nsinit2<<<dim3(B_), 256, 0, stream>>>(A, Xa, Ya);
  k_ns<<<dim3(4,4,64), 256, 0, stream>>>(Xa, Ya, Xb, Yb);
  k_ns<<<dim3(4,4,64), 256, 0, stream>>>(Xb, Yb, Xa, Ya);
  k_ns<<<dim3(4,4,64), 256, 0, stream>>>(Xa, Ya, Xb, Yb);
  (void)hipMemsetAsync(w, 0, (size_t)B_*NP*sizeof(float), stream);
  k_admm6<<<dim3(25*B_), 256, 0, stream>>>(Xb, p, w);
  k_finish<<<dim3(B_), 256, 0, stream>>>(w, v, mlg, mlb, mw, mb, outp);
}

// Round 8
// 678.366 us; speedup vs baseline: 16.0477x; 16.0477x over previous
//
#include <hip/hip_runtime.h>

#define B_ 32
#define NP 196
#define PD 768
#define DM 512
#define NC 1000
#define MAT (NP*NP)

typedef __attribute__((ext_vector_type(8))) short short8;
typedef __attribute__((ext_vector_type(16))) float f32x16;

__device__ inline unsigned short f2bf(float x) {
  union { float f; unsigned u; } c; c.f = x;
  unsigned r = c.u + 0x7FFFu + ((c.u >> 16) & 1u);
  return (unsigned short)(r >> 16);
}
__device__ inline float bf2f(unsigned short h) {
  union { unsigned u; float f; } c; c.u = ((unsigned)h) << 16; return c.f;
}

// ---------------- patchify + LN + pos ----------------
__global__ __launch_bounds__(256) void k_patchify(
    const float* __restrict__ img, const float* __restrict__ g,
    const float* __restrict__ be, const float* __restrict__ pos,
    float* __restrict__ x) {
  int bn = blockIdx.x;
  int b = bn / NP, n = bn % NP;
  int gh = n / 14, gw = n % 14;
  int t = threadIdx.x;
  float vals[3]; float s = 0.f, ss = 0.f;
  #pragma unroll
  for (int k = 0; k < 3; ++k) {
    int e = t + (k << 8);
    int inner = e & 255;
    int ph = inner >> 4, pw = inner & 15;
    float v = img[((b*3 + k)*224 + gh*16 + ph)*224 + gw*16 + pw];
    vals[k] = v; s += v; ss += v*v;
  }
  __shared__ float rb[8];
  for (int o = 32; o; o >>= 1) { s += __shfl_down(s,o); ss += __shfl_down(ss,o); }
  if ((t & 63) == 0) { rb[t>>6] = s; rb[4+(t>>6)] = ss; }
  __syncthreads();
  float S = rb[0]+rb[1]+rb[2]+rb[3], SS = rb[4]+rb[5]+rb[6]+rb[7];
  float mu = S * (1.f/768.f);
  float var = SS * (1.f/768.f) - mu*mu;
  float inv = rsqrtf(var + 1e-5f);
  #pragma unroll
  for (int k = 0; k < 3; ++k) {
    int e = t + (k << 8);
    x[(size_t)bn*PD + e] = (vals[k]-mu)*inv*g[e] + be[e] + pos[n*PD + e];
  }
}

// ---------------- merged Q/V GEMM: M=6272 K=768 N=512 (64x64 tile) ----------------
__global__ __launch_bounds__(256) void k_qv(
    const float* __restrict__ A,
    const float* __restrict__ wq, const float* __restrict__ bq,
    const float* __restrict__ wv, const float* __restrict__ bv,
    float* __restrict__ qo, float* __restrict__ vo) {
  const float* W    = blockIdx.z ? wv : wq;
  const float* bias = blockIdx.z ? bv : bq;
  float* out        = blockIdx.z ? vo : qo;
  __shared__ __align__(16) float As[16][68];
  __shared__ __align__(16) float Bs[16][64];
  int n0 = blockIdx.x * 64, m0 = blockIdx.y * 64;
  int t = threadIdx.x, tx = t & 15, ty = t >> 4;
  int alr = t >> 2, alc = (t & 3) << 2;
  int blr = t >> 4, blc = (t & 15) << 2;
  float acc[4][4] = {};
  for (int k0 = 0; k0 < 768; k0 += 16) {
    float4 av = *reinterpret_cast<const float4*>(&A[(size_t)(m0+alr)*768 + k0 + alc]);
    float4 bvv = *reinterpret_cast<const float4*>(&W[(size_t)(k0+blr)*512 + n0 + blc]);
    As[alc+0][alr] = av.x; As[alc+1][alr] = av.y;
    As[alc+2][alr] = av.z; As[alc+3][alr] = av.w;
    *reinterpret_cast<float4*>(&Bs[blr][blc]) = bvv;
    __syncthreads();
    #pragma unroll
    for (int kt = 0; kt < 16; ++kt) {
      float a4[4], b4[4];
      *reinterpret_cast<float4*>(a4) = *reinterpret_cast<const float4*>(&As[kt][ty<<2]);
      *reinterpret_cast<float4*>(b4) = *reinterpret_cast<const float4*>(&Bs[kt][tx<<2]);
      #pragma unroll
      for (int i = 0; i < 4; ++i)
        #pragma unroll
        for (int j = 0; j < 4; ++j) acc[i][j] += a4[i]*b4[j];
    }
    __syncthreads();
  }
  float4 bb = *reinterpret_cast<const float4*>(&bias[n0 + (tx<<2)]);
  float bb4[4] = {bb.x, bb.y, bb.z, bb.w};
  #pragma unroll
  for (int i = 0; i < 4; ++i) {
    float4 o;
    o.x = acc[i][0]+bb4[0]; o.y = acc[i][1]+bb4[1];
    o.z = acc[i][2]+bb4[2]; o.w = acc[i][3]+bb4[3];
    *reinterpret_cast<float4*>(&out[(size_t)(m0+(ty<<2)+i)*512 + n0 + (tx<<2)]) = o;
  }
}

// ---------------- merged row LayerNorm for q (scale 1) and v (scale 1/196) ----------------
__global__ __launch_bounds__(256) void k_ln2(
    float* __restrict__ q, float* __restrict__ v,
    const float* __restrict__ gq, const float* __restrict__ bq,
    const float* __restrict__ gv, const float* __restrict__ bv) {
  int r = blockIdx.x; bool hv = (r >= B_*NP); if (hv) r -= B_*NP;
  float* X = hv ? v : q;
  const float* g  = hv ? gv : gq;
  const float* be = hv ? bv : bq;
  float scale = hv ? (1.f/196.f) : 1.f;
  int t = threadIdx.x;
  float v0 = X[(size_t)r*512 + t], v1 = X[(size_t)r*512 + 256 + t];
  float s = v0+v1, ss = v0*v0+v1*v1;
  __shared__ float rb[8];
  for (int o = 32; o; o >>= 1) { s += __shfl_down(s,o); ss += __shfl_down(ss,o); }
  if ((t&63)==0) { rb[t>>6]=s; rb[4+(t>>6)]=ss; }
  __syncthreads();
  float S = rb[0]+rb[1]+rb[2]+rb[3], SS = rb[4]+rb[5]+rb[6]+rb[7];
  float mu = S*(1.f/512.f), var = SS*(1.f/512.f)-mu*mu;
  float inv = rsqrtf(var+1e-5f);
  X[(size_t)r*512+t]     = ((v0-mu)*inv*g[t]+be[t])*scale;
  X[(size_t)r*512+256+t] = ((v1-mu)*inv*g[t+256]+be[t+256])*scale;
}

// ---------------- merged Gram: z<32: A=2VV^T+I ; z>=32: p=-2QV^T+1/196 ----------------
__global__ __launch_bounds__(256) void k_gram(
    const float* __restrict__ q, const float* __restrict__ v,
    float* __restrict__ Ao, float* __restrict__ po) {
  int zz = blockIdx.z; int b = zz & 31; bool hp = (zz >= 32);
  float alpha  = hp ? -2.f : 2.f;
  float diagAdd = hp ? 0.f : 1.f;
  float cAdd   = hp ? (1.f/196.f) : 0.f;
  const float* Xb = (hp ? q : v) + (size_t)b*NP*512;
  const float* Yb = v + (size_t)b*NP*512;
  float* out = (hp ? po : Ao) + (size_t)b*MAT;
  int c0 = blockIdx.x * 64, r0 = blockIdx.y * 64;
  __shared__ __align__(16) float Xs[16][68];
  __shared__ __align__(16) float Ys[16][68];
  int t = threadIdx.x, tx = t & 15, ty = t >> 4;
  int lr = t >> 2, lc4 = (t & 3) << 2;
  float acc[4][4] = {};
  int xr = min(r0 + lr, NP-1), yr = min(c0 + lr, NP-1);
  for (int k0 = 0; k0 < 512; k0 += 16) {
    float4 xv = *reinterpret_cast<const float4*>(&Xb[(size_t)xr*512 + k0 + lc4]);
    float4 yv = *reinterpret_cast<const float4*>(&Yb[(size_t)yr*512 + k0 + lc4]);
    Xs[lc4+0][lr] = xv.x; Xs[lc4+1][lr] = xv.y;
    Xs[lc4+2][lr] = xv.z; Xs[lc4+3][lr] = xv.w;
    Ys[lc4+0][lr] = yv.x; Ys[lc4+1][lr] = yv.y;
    Ys[lc4+2][lr] = yv.z; Ys[lc4+3][lr] = yv.w;
    __syncthreads();
    #pragma unroll
    for (int kt = 0; kt < 16; ++kt) {
      float a4[4], b4[4];
      *reinterpret_cast<float4*>(a4) = *reinterpret_cast<const float4*>(&Xs[kt][ty<<2]);
      *reinterpret_cast<float4*>(b4) = *reinterpret_cast<const float4*>(&Ys[kt][tx<<2]);
      #pragma unroll
      for (int i = 0; i < 4; ++i)
        #pragma unroll
        for (int j = 0; j < 4; ++j) acc[i][j] += a4[i]*b4[j];
    }
    __syncthreads();
  }
  #pragma unroll
  for (int i = 0; i < 4; ++i) {
    int r = r0 + (ty<<2) + i; if (r >= NP) continue;
    #pragma unroll
    for (int j = 0; j < 4; ++j) {
      int c = c0 + (tx<<2) + j; if (c >= NP) continue;
      out[(size_t)r*NP + c] = alpha*acc[i][j] + cAdd + (r==c ? diagAdd : 0.f);
    }
  }
}

// ---------------- NS init: ninf bound, X0 = c*I, Y0 = c*A (Y tracks A@X) ----------------
__global__ __launch_bounds__(256) void k_nsinit2(
    const float* __restrict__ A, float* __restrict__ X, float* __restrict__ Y) {
  int b = blockIdx.x, t = threadIdx.x;
  const float* Ab = A + (size_t)b*MAT;
  __shared__ float sm[256];
  float lm = 0.f;
  if (t < NP) {
    float s = 0.f;
    for (int j = 0; j < NP; ++j) {
      float v = Ab[t*NP + j];
      if (j == t) v -= 1.f;
      s += fabsf(v);
    }
    lm = s;
  }
  sm[t] = lm; __syncthreads();
  for (int o = 128; o; o >>= 1) { if (t < o) sm[t] = fmaxf(sm[t], sm[t+o]); __syncthreads(); }
  float cc = 2.f / (2.f + sm[0]);
  float* Xb = X + (size_t)b*MAT;
  float* Yb = Y + (size_t)b*MAT;
  for (int idx = t; idx < MAT; idx += 256) {
    Xb[idx] = (idx % (NP+1) == 0) ? cc : 0.f;
    Yb[idx] = cc * Ab[idx];
  }
}

// ---------------- NS iter: z<32: Xn=2X-X@Y ; z>=32: Yn=2Y-Y@Y ----------------
__global__ __launch_bounds__(256) void k_ns(
    const float* __restrict__ X, const float* __restrict__ Y,
    float* __restrict__ Xn, float* __restrict__ Yn) {
  int zz = blockIdx.z; int b = zz & 31; bool hy = (zz >= 32);
  const float* Lb = (hy ? Y : X) + (size_t)b*MAT;
  const float* Rb = Y + (size_t)b*MAT;
  float* Ob = (hy ? Yn : Xn) + (size_t)b*MAT;
  int c0 = blockIdx.x * 64, r0 = blockIdx.y * 64;
  __shared__ __align__(16) float Ls[16][68];
  __shared__ __align__(16) float Rs[16][64];
  int t = threadIdx.x, tx = t & 15, ty = t >> 4;
  int alr = t >> 2, alc = (t & 3) << 2;
  int blr = t >> 4, blc = (t & 15) << 2;
  float acc[4][4] = {};
  int lrow = min(r0 + alr, NP-1);
  for (int k0 = 0; k0 < NP; k0 += 16) {
    float4 lv = {0.f,0.f,0.f,0.f};
    if (k0 + alc < NP) lv = *reinterpret_cast<const float4*>(&Lb[(size_t)lrow*NP + k0 + alc]);
    float4 rv = {0.f,0.f,0.f,0.f};
    if (k0 + blr < NP) rv = *reinterpret_cast<const float4*>(&Rb[(size_t)(k0+blr)*NP + c0 + blc]);
    Ls[alc+0][alr] = lv.x; Ls[alc+1][alr] = lv.y;
    Ls[alc+2][alr] = lv.z; Ls[alc+3][alr] = lv.w;
    *reinterpret_cast<float4*>(&Rs[blr][blc]) = rv;
    __syncthreads();
    #pragma unroll
    for (int kt = 0; kt < 16; ++kt) {
      float a4[4], b4[4];
      *reinterpret_cast<float4*>(a4) = *reinterpret_cast<const float4*>(&Ls[kt][ty<<2]);
      *reinterpret_cast<float4*>(b4) = *reinterpret_cast<const float4*>(&Rs[kt][tx<<2]);
      #pragma unroll
      for (int i = 0; i < 4; ++i)
        #pragma unroll
        for (int j = 0; j < 4; ++j) acc[i][j] += a4[i]*b4[j];
    }
    __syncthreads();
  }
  #pragma unroll
  for (int i = 0; i < 4; ++i) {
    int r = r0 + (ty<<2) + i; if (r >= NP) continue;
    #pragma unroll
    for (int j = 0; j < 4; ++j) {
      int c = c0 + (tx<<2) + j; if (c >= NP) continue;
      Ob[(size_t)r*NP + c] = 2.f*Lb[(size_t)r*NP + c] - acc[i][j];
    }
  }
}

// ---------------- Minv -> bf16 hi/lo split, pre-swizzled into MFMA A-fragment order ----
// A-frag for mfma_f32_32x32x16_bf16: lane l holds A[m = l&31][k = ks*16 + (l>>5)*8 + j].
// Storage: [b][mtile 7][kstep 13][lane 64][j 8] ushort, m/k >= 196 zero-padded.
__global__ __launch_bounds__(256) void k_swz(
    const float* __restrict__ Minv,
    unsigned short* __restrict__ Ahi, unsigned short* __restrict__ Alo) {
  int bid = blockIdx.x;          // 32*7
  int b = bid & 31, mt = bid >> 5;
  int t = threadIdx.x;
  int l = t & 63, jp = (t >> 6) * 2;
  int m = mt*32 + (l & 31);
  const float* Mb = Minv + (size_t)b*MAT;
  size_t obase = ((size_t)(b*7 + mt)*13)*512;
  for (int ks = 0; ks < 13; ++ks) {
    #pragma unroll
    for (int jo = 0; jo < 2; ++jo) {
      int j = jp + jo;
      int k = ks*16 + (l>>5)*8 + j;
      float v = (m < NP && k < NP) ? Mb[(size_t)m*NP + k] : 0.f;
      unsigned short hh = f2bf(v);
      unsigned short ll = f2bf(v - bf2f(hh));
      size_t idx = obase + (size_t)ks*512 + l*8 + j;
      Ahi[idx] = hh; Alo[idx] = ll;
    }
  }
}

// ---------------- fused 50-iter ADMM v7: bf16-split MFMA ----------------
// 224 blocks (7 token-tiles x 32 batches; all co-resident), 448 thr = 7 waves.
// Wave wv owns m-tile [32wv, 32wv+32). Per iter: X(32m x 32n) = Minv @ RHS via
// 13 ksteps x 3 split-MFMAs (hi*hi + hi*lo + lo*hi, fp32 acc; err ~2^-18).
// A-frags streamed pre-swizzled from L2 (1 coalesced 16B load/lane/frag).
// RHS lives in LDS as B-fragments (hi/lo bf16). Update phase is register-local
// via C-layout (col=lane&31, row=(reg&3)+8*(reg>>2)+4*(lane>>5)); writes next
// iter's B-frags directly. No cross-wave reduction in the loop.
__global__ __launch_bounds__(448) void k_admm7(
    const unsigned short* __restrict__ Ahi, const unsigned short* __restrict__ Alo,
    const float* __restrict__ P, float* __restrict__ w) {
  int bid = blockIdx.x;
  int b = bid & 31, tt = bid >> 5;      // batch, token-tile (0..6)
  int t = threadIdx.x;
  int wv = t >> 6;                      // wave = m-tile 0..6
  int l = t & 63;
  int n_l = l & 31, h = l >> 5;
  int n = tt*32 + n_l;                  // token (pad >=196 masked at end)
  int mt = wv;

  __shared__ __align__(16) unsigned short Bhi[26*32*8];  // [k>>3][n][j]
  __shared__ __align__(16) unsigned short Blo[26*32*8];
  __shared__ float ssum[7][32];

  float z[16], u[16], pr[16];
  int ngc = min(n, NP-1);
  const float* prow = P + ((size_t)b*NP + ngc)*NP;
  #pragma unroll
  for (int r = 0; r < 16; ++r) {
    int m = mt*32 + (r&3) + 8*(r>>2) + 4*h;
    pr[r] = prow[min(m, NP-1)];
    z[r] = 0.f; u[r] = 0.f;
  }
  // initial rhs = -p -> B-frags
  #pragma unroll
  for (int r = 0; r < 16; ++r) {
    int m = mt*32 + (r&3) + 8*(r>>2) + 4*h;
    float rhs = -pr[r];
    unsigned short hh = f2bf(rhs);
    unsigned short ll = f2bf(rhs - bf2f(hh));
    int idx = ((m >> 3)*32 + n_l)*8 + (m & 7);
    Bhi[idx] = hh; Blo[idx] = ll;
  }
  __syncthreads();

  const unsigned short* ah_base = Ahi + ((size_t)(b*7 + mt)*13)*512 + l*8;
  const unsigned short* al_base = Alo + ((size_t)(b*7 + mt)*13)*512 + l*8;
  int boff = (h*32 + n_l)*8;            // B-frag base for this lane (per kstep: +512)

  for (int it = 0; it < 50; ++it) {
    f32x16 acc1, acc2, acc3;
    #pragma unroll
    for (int i = 0; i < 16; ++i) { acc1[i] = 0.f; acc2[i] = 0.f; acc3[i] = 0.f; }
    #pragma unroll
    for (int ks = 0; ks < 13; ++ks) {
      short8 ah = *reinterpret_cast<const short8*>(ah_base + (size_t)ks*512);
      short8 al = *reinterpret_cast<const short8*>(al_base + (size_t)ks*512);
      short8 bh = *reinterpret_cast<const short8*>(&Bhi[ks*512 + boff]);
      short8 bl = *reinterpret_cast<const short8*>(&Blo[ks*512 + boff]);
      acc1 = __builtin_amdgcn_mfma_f32_32x32x16_bf16(ah, bh, acc1, 0, 0, 0);
      acc2 = __builtin_amdgcn_mfma_f32_32x32x16_bf16(ah, bl, acc2, 0, 0, 0);
      acc3 = __builtin_amdgcn_mfma_f32_32x32x16_bf16(al, bh, acc3, 0, 0, 0);
    }
    __syncthreads();   // all B reads complete before rewrite
    #pragma unroll
    for (int r = 0; r < 16; ++r) {
      int m = mt*32 + (r&3) + 8*(r>>2) + 4*h;
      float x = acc1[r] + acc2[r] + acc3[r];
      float xpu = x + u[r];
      float zz = fminf(fmaxf(xpu, 0.f), 1.f);
      u[r] = xpu - zz;
      z[r] = zz;
      float rhs = zz - u[r] - pr[r];
      unsigned short hh = f2bf(rhs);
      unsigned short ll = f2bf(rhs - bf2f(hh));
      int idx = ((m >> 3)*32 + n_l)*8 + (m & 7);
      Bhi[idx] = hh; Blo[idx] = ll;
    }
    __syncthreads();   // writes visible to all waves
  }

  // normalization: s[n] = sum_m z (m < 196 only)
  float s = 0.f;
  #pragma unroll
  for (int r = 0; r < 16; ++r) {
    int m = mt*32 + (r&3) + 8*(r>>2) + 4*h;
    if (m < NP) s += z[r];
  }
  s += __shfl_xor(s, 32, 64);           // combine the two m-halves (same n)
  if (l < 32) ssum[wv][n_l] = s;
  __syncthreads();
  float stot = 0.f;
  #pragma unroll
  for (int q = 0; q < 7; ++q) stot += ssum[q][n_l];
  float inv = (n < NP) ? 1.f/(stot + 1e-10f) : 0.f;
  // w[b][m] += sum_n z*inv/196 : butterfly over the 32 n-lanes of each half
  #pragma unroll
  for (int r = 0; r < 16; ++r) {
    float c = z[r] * inv * (1.f/196.f);
    #pragma unroll
    for (int o = 16; o; o >>= 1) c += __shfl_xor(c, o, 64);
    if (n_l == 0) {
      int m = mt*32 + (r&3) + 8*(r>>2) + 4*h;
      if (m < NP) atomicAdd(&w[b*NP + m], c);
    }
  }
}

// ---------------- fused pooled + LN + head + softmax ----------------
__global__ __launch_bounds__(256) void k_finish(
    const float* __restrict__ w, const float* __restrict__ V,
    const float* __restrict__ g, const float* __restrict__ be,
    const float* __restrict__ Wm, const float* __restrict__ bm,
    float* __restrict__ out) {
  int b = blockIdx.x, t = threadIdx.x;
  __shared__ float ws_[NP];
  __shared__ float pl[512];
  __shared__ float rb[8];
  if (t < NP) ws_[t] = w[b*NP + t];
  __syncthreads();
  const float* Vb = V + (size_t)b*NP*512;
  float a0 = 0.f, a1 = 0.f;
  #pragma unroll 4
  for (int m = 0; m < NP; ++m) {
    float wm = ws_[m];
    a0 = fmaf(wm, Vb[(size_t)m*512 + t], a0);
    a1 = fmaf(wm, Vb[(size_t)m*512 + 256 + t], a1);
  }
  float s = a0+a1, ss = a0*a0+a1*a1;
  for (int o = 32; o; o >>= 1) { s += __shfl_down(s,o); ss += __shfl_down(ss,o); }
  if ((t&63)==0) { rb[t>>6]=s; rb[4+(t>>6)]=ss; }
  __syncthreads();
  float S = rb[0]+rb[1]+rb[2]+rb[3], SS = rb[4]+rb[5]+rb[6]+rb[7];
  float mu = S*(1.f/512.f), var = SS*(1.f/512.f)-mu*mu, inv = rsqrtf(var+1e-5f);
  pl[t]     = (a0-mu)*inv*g[t] + be[t];
  pl[t+256] = (a1-mu)*inv*g[t+256] + be[t+256];
  __syncthreads();
  float lg[4];
  #pragma unroll
  for (int qq = 0; qq < 4; ++qq) {
    int c = t + (qq<<8);
    float a = -1e30f;
    if (c < NC) {
      a = bm[c];
      #pragma unroll 8
      for (int k = 0; k < 512; ++k) a += pl[k]*Wm[(size_t)k*NC + c];
    }
    lg[qq] = a;
  }
  float mx = fmaxf(fmaxf(lg[0],lg[1]), fmaxf(lg[2],lg[3]));
  for (int o = 32; o; o >>= 1) mx = fmaxf(mx, __shfl_down(mx,o));
  __syncthreads();
  if ((t&63)==0) rb[t>>6] = mx;
  __syncthreads();
  float MX = fmaxf(fmaxf(rb[0],rb[1]), fmaxf(rb[2],rb[3]));
  float es = 0.f, ev[4];
  #pragma unroll
  for (int qq = 0; qq < 4; ++qq) {
    int c = t + (qq<<8);
    ev[qq] = (c < NC) ? __expf(lg[qq]-MX) : 0.f;
    es += ev[qq];
  }
  for (int o = 32; o; o >>= 1) es += __shfl_down(es,o);
  __syncthreads();
  if ((t&63)==0) rb[4+(t>>6)] = es;
  __syncthreads();
  float SUM = rb[4]+rb[5]+rb[6]+rb[7];
  float rinv = 1.f/SUM;
  #pragma unroll
  for (int qq = 0; qq < 4; ++qq) {
    int c = t + (qq<<8);
    if (c < NC) out[(size_t)b*NC + c] = ev[qq]*rinv;
  }
}

extern "C" void kernel_launch(void* const* d_in, const int* in_sizes, int n_in,
                              void* d_out, int out_size, void* d_ws, size_t ws_size,
                              hipStream_t stream) {
  const float* img = (const float*)d_in[0];
  const float* lpg = (const float*)d_in[1];
  const float* lpb = (const float*)d_in[2];
  const float* wqw = (const float*)d_in[3];
  const float* wqb = (const float*)d_in[4];
  const float* lqg = (const float*)d_in[5];
  const float* lqb = (const float*)d_in[6];
  const float* wvw = (const float*)d_in[7];
  const float* wvb = (const float*)d_in[8];
  const float* lvg = (const float*)d_in[9];
  const float* lvb = (const float*)d_in[10];
  const float* pos = (const float*)d_in[11];
  const float* mlg = (const float*)d_in[12];
  const float* mlb = (const float*)d_in[13];
  const float* mw  = (const float*)d_in[14];
  const float* mb  = (const float*)d_in[15];
  float* outp = (float*)d_out;

  float* ws = (float*)d_ws;
  size_t off = 0;
  float* x  = ws + off;      off += (size_t)B_*NP*PD;
  float* q  = ws + off;      off += (size_t)B_*NP*DM;
  float* v  = ws + off;      off += (size_t)B_*NP*DM;
  size_t matp = (size_t)B_*MAT + 256;
  float* A  = ws + off;      off += matp;
  float* p  = ws + off;      off += matp;
  float* Xa = ws + off;      off += matp;
  float* Xb = ws + off;      off += matp;
  float* Ya = ws + off;      off += matp;
  float* Yb = A;                            // alias: A dead after k_nsinit2
  float* w  = ws + off;      off += (size_t)B_*NP;
  off = (off + 3) & ~(size_t)3;             // 16B align for short8 loads
  size_t swzE = (size_t)B_*7*13*512;        // ushort elements per component
  unsigned short* Ahi = (unsigned short*)(ws + off); off += swzE/2;
  unsigned short* Alo = (unsigned short*)(ws + off); off += swzE/2;
  if (ws_size < off * sizeof(float)) return;

  k_patchify<<<dim3(B_*NP), 256, 0, stream>>>(img, lpg, lpb, pos, x);
  k_qv<<<dim3(8, 98, 2), 256, 0, stream>>>(x, wqw, wqb, wvw, wvb, q, v);
  k_ln2<<<dim3(2*B_*NP), 256, 0, stream>>>(q, v, lqg, lqb, lvg, lvb);
  k_gram<<<dim3(4,4,64), 256, 0, stream>>>(q, v, A, p);
  k_nsinit2<<<dim3(B_), 256, 0, stream>>>(A, Xa, Ya);
  k_ns<<<dim3(4,4,64), 256, 0, stream>>>(Xa, Ya, Xb, Yb);
  k_ns<<<dim3(4,4,64), 256, 0, stream>>>(Xb, Yb, Xa, Ya);
  k_ns<<<dim3(4,4,64), 256, 0, stream>>>(Xa, Ya, Xb, Yb);
  k_swz<<<dim3(B_*7), 256, 0, stream>>>(Xb, Ahi, Alo);
  (void)hipMemsetAsync(w, 0, (size_t)B_*NP*sizeof(float), stream);
  k_admm7<<<dim3(7*B_), 448, 0, stream>>>(Ahi, Alo, p, w);
  k_finish<<<dim3(B_), 256, 0, stream>>>(w, v, mlg, mlb, mw, mb, outp);
}

// Round 9
// 655.966 us; speedup vs baseline: 16.5957x; 1.0341x over previous
//
#include <hip/hip_runtime.h>

#define B_ 32
#define NP 196
#define PD 768
#define DM 512
#define NC 1000
#define MAT (NP*NP)

typedef __attribute__((ext_vector_type(8))) short short8;
typedef __attribute__((ext_vector_type(16))) float f32x16;

__device__ inline unsigned short f2bf(float x) {
  union { float f; unsigned u; } c; c.f = x;
  unsigned r = c.u + 0x7FFFu + ((c.u >> 16) & 1u);
  return (unsigned short)(r >> 16);
}
__device__ inline float bf2f(unsigned short h) {
  union { unsigned u; float f; } c; c.u = ((unsigned)h) << 16; return c.f;
}

// ---------------- patchify + LN + pos -> X in A-fragment hi/lo bf16 layout ----------------
// A-frag (32x32x16 MFMA): element (m,k) -> idx = ((mt*48+ks)*64 + (m&31) + 32*((k>>3)&1))*8 + (k&7)
__global__ __launch_bounds__(256) void k_patchify(
    const float* __restrict__ img, const float* __restrict__ g,
    const float* __restrict__ be, const float* __restrict__ pos,
    unsigned short* __restrict__ Xh, unsigned short* __restrict__ Xl) {
  int bn = blockIdx.x;
  int b = bn / NP, n = bn % NP;
  int gh = n / 14, gw = n % 14;
  int t = threadIdx.x;
  float vals[3]; float s = 0.f, ss = 0.f;
  #pragma unroll
  for (int k = 0; k < 3; ++k) {
    int e = t + (k << 8);
    int inner = e & 255;
    int ph = inner >> 4, pw = inner & 15;
    float v = img[((b*3 + k)*224 + gh*16 + ph)*224 + gw*16 + pw];
    vals[k] = v; s += v; ss += v*v;
  }
  __shared__ float rb[8];
  for (int o = 32; o; o >>= 1) { s += __shfl_down(s,o); ss += __shfl_down(ss,o); }
  if ((t & 63) == 0) { rb[t>>6] = s; rb[4+(t>>6)] = ss; }
  __syncthreads();
  float S = rb[0]+rb[1]+rb[2]+rb[3], SS = rb[4]+rb[5]+rb[6]+rb[7];
  float mu = S * (1.f/768.f);
  float var = SS * (1.f/768.f) - mu*mu;
  float inv = rsqrtf(var + 1e-5f);
  int mt = bn >> 5, ml = bn & 31;
  size_t base = (size_t)mt * 48 * 512;
  #pragma unroll
  for (int k = 0; k < 3; ++k) {
    int e = t + (k << 8);
    float val = (vals[k]-mu)*inv*g[e] + be[e] + pos[n*PD + e];
    unsigned short hh = f2bf(val);
    unsigned short ll = f2bf(val - bf2f(hh));
    int ks = e >> 4, h = (e >> 3) & 1, j = e & 7;
    size_t idx = base + ((size_t)ks*64 + ml + 32*h)*8 + j;
    Xh[idx] = hh; Xl[idx] = ll;
  }
}

// ---------------- weight -> B-fragment hi/lo bf16 layout ----------------
// B-frag: element (k,n) -> idx = ((nt*48+ks)*64 + (n&31) + 32*((k>>3)&1))*8 + (k&7)
__global__ __launch_bounds__(256) void k_wswz(
    const float* __restrict__ W,
    unsigned short* __restrict__ Bh, unsigned short* __restrict__ Bl) {
  int k = blockIdx.x;           // 0..767
  int t = threadIdx.x;
  int ks = k >> 4, h = (k >> 3) & 1, j = k & 7;
  #pragma unroll
  for (int q = 0; q < 2; ++q) {
    int n = t + (q << 8);
    float v = W[(size_t)k*512 + n];
    unsigned short hh = f2bf(v);
    unsigned short ll = f2bf(v - bf2f(hh));
    size_t idx = (((size_t)(n>>5)*48 + ks)*64 + (n&31) + 32*h)*8 + j;
    Bh[idx] = hh; Bl[idx] = ll;
  }
}

// ---------------- Q/V projection via bf16-split MFMA (no LDS, frags from L2/L3) ----------
// grid (196 mtiles, 2 proj), 256 thr = 4 waves; wave w owns ntiles [4w,4w+4).
// Per kstep: 2 A-frag + 8 B-frag 16B loads, 12 MFMAs (hi*hi -> acc1, hi*lo+lo*hi -> acc2).
// M=6272=196*32, N=512=16*32, K=768=48*16: exact, no masking.
__global__ __launch_bounds__(256, 1) void k_qv_mfma(
    const unsigned short* __restrict__ Xh, const unsigned short* __restrict__ Xl,
    const unsigned short* __restrict__ Wqh, const unsigned short* __restrict__ Wql,
    const unsigned short* __restrict__ Wvh, const unsigned short* __restrict__ Wvl,
    const float* __restrict__ bq, const float* __restrict__ bv,
    float* __restrict__ qo, float* __restrict__ vo) {
  int mt = blockIdx.x, proj = blockIdx.y;
  const unsigned short* Bh = proj ? Wvh : Wqh;
  const unsigned short* Bl = proj ? Wvl : Wql;
  const float* bias = proj ? bv : bq;
  float* out = proj ? vo : qo;
  int t = threadIdx.x, wv = t >> 6, l = t & 63;
  int n_l = l & 31, h = l >> 5;
  const unsigned short* ah_p = Xh + (size_t)mt*48*512 + l*8;
  const unsigned short* al_p = Xl + (size_t)mt*48*512 + l*8;
  f32x16 acc1[4], acc2[4];
  #pragma unroll
  for (int q4 = 0; q4 < 4; ++q4)
    #pragma unroll
    for (int i = 0; i < 16; ++i) { acc1[q4][i] = 0.f; acc2[q4][i] = 0.f; }
  #pragma unroll 2
  for (int ks = 0; ks < 48; ++ks) {
    short8 ah = *reinterpret_cast<const short8*>(ah_p + (size_t)ks*512);
    short8 al = *reinterpret_cast<const short8*>(al_p + (size_t)ks*512);
    #pragma unroll
    for (int q4 = 0; q4 < 4; ++q4) {
      int nt = wv*4 + q4;
      size_t bo = ((size_t)nt*48 + ks)*512 + l*8;
      short8 bh = *reinterpret_cast<const short8*>(Bh + bo);
      short8 bl8 = *reinterpret_cast<const short8*>(Bl + bo);
      acc1[q4] = __builtin_amdgcn_mfma_f32_32x32x16_bf16(ah, bh,  acc1[q4], 0, 0, 0);
      acc2[q4] = __builtin_amdgcn_mfma_f32_32x32x16_bf16(ah, bl8, acc2[q4], 0, 0, 0);
      acc2[q4] = __builtin_amdgcn_mfma_f32_32x32x16_bf16(al, bh,  acc2[q4], 0, 0, 0);
    }
  }
  #pragma unroll
  for (int q4 = 0; q4 < 4; ++q4) {
    int nt = wv*4 + q4;
    float bb = bias[nt*32 + n_l];
    #pragma unroll
    for (int r = 0; r < 16; ++r) {
      int rl = (r&3) + 8*(r>>2) + 4*h;         // C layout: row local
      out[(size_t)(mt*32 + rl)*512 + nt*32 + n_l] = acc1[q4][r] + acc2[q4][r] + bb;
    }
  }
}

// ---------------- merged row LayerNorm for q (scale 1) and v (scale 1/196) ----------------
__global__ __launch_bounds__(256) void k_ln2(
    float* __restrict__ q, float* __restrict__ v,
    const float* __restrict__ gq, const float* __restrict__ bq,
    const float* __restrict__ gv, const float* __restrict__ bv) {
  int r = blockIdx.x; bool hv = (r >= B_*NP); if (hv) r -= B_*NP;
  float* X = hv ? v : q;
  const float* g  = hv ? gv : gq;
  const float* be = hv ? bv : bq;
  float scale = hv ? (1.f/196.f) : 1.f;
  int t = threadIdx.x;
  float v0 = X[(size_t)r*512 + t], v1 = X[(size_t)r*512 + 256 + t];
  float s = v0+v1, ss = v0*v0+v1*v1;
  __shared__ float rb[8];
  for (int o = 32; o; o >>= 1) { s += __shfl_down(s,o); ss += __shfl_down(ss,o); }
  if ((t&63)==0) { rb[t>>6]=s; rb[4+(t>>6)]=ss; }
  __syncthreads();
  float S = rb[0]+rb[1]+rb[2]+rb[3], SS = rb[4]+rb[5]+rb[6]+rb[7];
  float mu = S*(1.f/512.f), var = SS*(1.f/512.f)-mu*mu;
  float inv = rsqrtf(var+1e-5f);
  X[(size_t)r*512+t]     = ((v0-mu)*inv*g[t]+be[t])*scale;
  X[(size_t)r*512+256+t] = ((v1-mu)*inv*g[t+256]+be[t+256])*scale;
}

// ---------------- merged Gram: z<32: A=2VV^T+I ; z>=32: p=-2QV^T+1/196 ----------------
__global__ __launch_bounds__(256) void k_gram(
    const float* __restrict__ q, const float* __restrict__ v,
    float* __restrict__ Ao, float* __restrict__ po) {
  int zz = blockIdx.z; int b = zz & 31; bool hp = (zz >= 32);
  float alpha  = hp ? -2.f : 2.f;
  float diagAdd = hp ? 0.f : 1.f;
  float cAdd   = hp ? (1.f/196.f) : 0.f;
  const float* Xb = (hp ? q : v) + (size_t)b*NP*512;
  const float* Yb = v + (size_t)b*NP*512;
  float* out = (hp ? po : Ao) + (size_t)b*MAT;
  int c0 = blockIdx.x * 64, r0 = blockIdx.y * 64;
  __shared__ __align__(16) float Xs[16][68];
  __shared__ __align__(16) float Ys[16][68];
  int t = threadIdx.x, tx = t & 15, ty = t >> 4;
  int lr = t >> 2, lc4 = (t & 3) << 2;
  float acc[4][4] = {};
  int xr = min(r0 + lr, NP-1), yr = min(c0 + lr, NP-1);
  for (int k0 = 0; k0 < 512; k0 += 16) {
    float4 xv = *reinterpret_cast<const float4*>(&Xb[(size_t)xr*512 + k0 + lc4]);
    float4 yv = *reinterpret_cast<const float4*>(&Yb[(size_t)yr*512 + k0 + lc4]);
    Xs[lc4+0][lr] = xv.x; Xs[lc4+1][lr] = xv.y;
    Xs[lc4+2][lr] = xv.z; Xs[lc4+3][lr] = xv.w;
    Ys[lc4+0][lr] = yv.x; Ys[lc4+1][lr] = yv.y;
    Ys[lc4+2][lr] = yv.z; Ys[lc4+3][lr] = yv.w;
    __syncthreads();
    #pragma unroll
    for (int kt = 0; kt < 16; ++kt) {
      float a4[4], b4[4];
      *reinterpret_cast<float4*>(a4) = *reinterpret_cast<const float4*>(&Xs[kt][ty<<2]);
      *reinterpret_cast<float4*>(b4) = *reinterpret_cast<const float4*>(&Ys[kt][tx<<2]);
      #pragma unroll
      for (int i = 0; i < 4; ++i)
        #pragma unroll
        for (int j = 0; j < 4; ++j) acc[i][j] += a4[i]*b4[j];
    }
    __syncthreads();
  }
  #pragma unroll
  for (int i = 0; i < 4; ++i) {
    int r = r0 + (ty<<2) + i; if (r >= NP) continue;
    #pragma unroll
    for (int j = 0; j < 4; ++j) {
      int c = c0 + (tx<<2) + j; if (c >= NP) continue;
      out[(size_t)r*NP + c] = alpha*acc[i][j] + cAdd + (r==c ? diagAdd : 0.f);
    }
  }
}

// ---------------- NS init: ninf bound, X0 = c*I, Y0 = c*A (Y tracks A@X) ----------------
__global__ __launch_bounds__(256) void k_nsinit2(
    const float* __restrict__ A, float* __restrict__ X, float* __restrict__ Y) {
  int b = blockIdx.x, t = threadIdx.x;
  const float* Ab = A + (size_t)b*MAT;
  __shared__ float sm[256];
  float lm = 0.f;
  if (t < NP) {
    float s = 0.f;
    for (int j = 0; j < NP; ++j) {
      float v = Ab[t*NP + j];
      if (j == t) v -= 1.f;
      s += fabsf(v);
    }
    lm = s;
  }
  sm[t] = lm; __syncthreads();
  for (int o = 128; o; o >>= 1) { if (t < o) sm[t] = fmaxf(sm[t], sm[t+o]); __syncthreads(); }
  float cc = 2.f / (2.f + sm[0]);
  float* Xb = X + (size_t)b*MAT;
  float* Yb = Y + (size_t)b*MAT;
  for (int idx = t; idx < MAT; idx += 256) {
    Xb[idx] = (idx % (NP+1) == 0) ? cc : 0.f;
    Yb[idx] = cc * Ab[idx];
  }
}

// ---------------- NS iter: z<32: Xn=2X-X@Y ; z>=32: Yn=2Y-Y@Y ----------------
__global__ __launch_bounds__(256) void k_ns(
    const float* __restrict__ X, const float* __restrict__ Y,
    float* __restrict__ Xn, float* __restrict__ Yn) {
  int zz = blockIdx.z; int b = zz & 31; bool hy = (zz >= 32);
  const float* Lb = (hy ? Y : X) + (size_t)b*MAT;
  const float* Rb = Y + (size_t)b*MAT;
  float* Ob = (hy ? Yn : Xn) + (size_t)b*MAT;
  int c0 = blockIdx.x * 64, r0 = blockIdx.y * 64;
  __shared__ __align__(16) float Ls[16][68];
  __shared__ __align__(16) float Rs[16][64];
  int t = threadIdx.x, tx = t & 15, ty = t >> 4;
  int alr = t >> 2, alc = (t & 3) << 2;
  int blr = t >> 4, blc = (t & 15) << 2;
  float acc[4][4] = {};
  int lrow = min(r0 + alr, NP-1);
  for (int k0 = 0; k0 < NP; k0 += 16) {
    float4 lv = {0.f,0.f,0.f,0.f};
    if (k0 + alc < NP) lv = *reinterpret_cast<const float4*>(&Lb[(size_t)lrow*NP + k0 + alc]);
    float4 rv = {0.f,0.f,0.f,0.f};
    if (k0 + blr < NP) rv = *reinterpret_cast<const float4*>(&Rb[(size_t)(k0+blr)*NP + c0 + blc]);
    Ls[alc+0][alr] = lv.x; Ls[alc+1][alr] = lv.y;
    Ls[alc+2][alr] = lv.z; Ls[alc+3][alr] = lv.w;
    *reinterpret_cast<float4*>(&Rs[blr][blc]) = rv;
    __syncthreads();
    #pragma unroll
    for (int kt = 0; kt < 16; ++kt) {
      float a4[4], b4[4];
      *reinterpret_cast<float4*>(a4) = *reinterpret_cast<const float4*>(&Ls[kt][ty<<2]);
      *reinterpret_cast<float4*>(b4) = *reinterpret_cast<const float4*>(&Rs[kt][tx<<2]);
      #pragma unroll
      for (int i = 0; i < 4; ++i)
        #pragma unroll
        for (int j = 0; j < 4; ++j) acc[i][j] += a4[i]*b4[j];
    }
    __syncthreads();
  }
  #pragma unroll
  for (int i = 0; i < 4; ++i) {
    int r = r0 + (ty<<2) + i; if (r >= NP) continue;
    #pragma unroll
    for (int j = 0; j < 4; ++j) {
      int c = c0 + (tx<<2) + j; if (c >= NP) continue;
      Ob[(size_t)r*NP + c] = 2.f*Lb[(size_t)r*NP + c] - acc[i][j];
    }
  }
}

// ---------------- Minv -> bf16 hi/lo split, pre-swizzled into MFMA A-fragment order ----
__global__ __launch_bounds__(256) void k_swz(
    const float* __restrict__ Minv,
    unsigned short* __restrict__ Ahi, unsigned short* __restrict__ Alo) {
  int bid = blockIdx.x;          // 32*7
  int b = bid & 31, mt = bid >> 5;
  int t = threadIdx.x;
  int l = t & 63, jp = (t >> 6) * 2;
  int m = mt*32 + (l & 31);
  const float* Mb = Minv + (size_t)b*MAT;
  size_t obase = ((size_t)(b*7 + mt)*13)*512;
  for (int ks = 0; ks < 13; ++ks) {
    #pragma unroll
    for (int jo = 0; jo < 2; ++jo) {
      int j = jp + jo;
      int k = ks*16 + (l>>5)*8 + j;
      float v = (m < NP && k < NP) ? Mb[(size_t)m*NP + k] : 0.f;
      unsigned short hh = f2bf(v);
      unsigned short ll = f2bf(v - bf2f(hh));
      size_t idx = obase + (size_t)ks*512 + l*8 + j;
      Ahi[idx] = hh; Alo[idx] = ll;
    }
  }
}

// ---------------- fused 50-iter ADMM: bf16-split MFMA (round-8 kernel, unchanged) ----------
__global__ __launch_bounds__(448) void k_admm7(
    const unsigned short* __restrict__ Ahi, const unsigned short* __restrict__ Alo,
    const float* __restrict__ P, float* __restrict__ w) {
  int bid = blockIdx.x;
  int b = bid & 31, tt = bid >> 5;
  int t = threadIdx.x;
  int wv = t >> 6;
  int l = t & 63;
  int n_l = l & 31, h = l >> 5;
  int n = tt*32 + n_l;
  int mt = wv;

  __shared__ __align__(16) unsigned short Bhi[26*32*8];
  __shared__ __align__(16) unsigned short Blo[26*32*8];
  __shared__ float ssum[7][32];

  float z[16], u[16], pr[16];
  int ngc = min(n, NP-1);
  const float* prow = P + ((size_t)b*NP + ngc)*NP;
  #pragma unroll
  for (int r = 0; r < 16; ++r) {
    int m = mt*32 + (r&3) + 8*(r>>2) + 4*h;
    pr[r] = prow[min(m, NP-1)];
    z[r] = 0.f; u[r] = 0.f;
  }
  #pragma unroll
  for (int r = 0; r < 16; ++r) {
    int m = mt*32 + (r&3) + 8*(r>>2) + 4*h;
    float rhs = -pr[r];
    unsigned short hh = f2bf(rhs);
    unsigned short ll = f2bf(rhs - bf2f(hh));
    int idx = ((m >> 3)*32 + n_l)*8 + (m & 7);
    Bhi[idx] = hh; Blo[idx] = ll;
  }
  __syncthreads();

  const unsigned short* ah_base = Ahi + ((size_t)(b*7 + mt)*13)*512 + l*8;
  const unsigned short* al_base = Alo + ((size_t)(b*7 + mt)*13)*512 + l*8;
  int boff = (h*32 + n_l)*8;

  for (int it = 0; it < 50; ++it) {
    f32x16 acc1, acc2, acc3;
    #pragma unroll
    for (int i = 0; i < 16; ++i) { acc1[i] = 0.f; acc2[i] = 0.f; acc3[i] = 0.f; }
    #pragma unroll
    for (int ks = 0; ks < 13; ++ks) {
      short8 ah = *reinterpret_cast<const short8*>(ah_base + (size_t)ks*512);
      short8 al = *reinterpret_cast<const short8*>(al_base + (size_t)ks*512);
      short8 bh = *reinterpret_cast<const short8*>(&Bhi[ks*512 + boff]);
      short8 bl = *reinterpret_cast<const short8*>(&Blo[ks*512 + boff]);
      acc1 = __builtin_amdgcn_mfma_f32_32x32x16_bf16(ah, bh, acc1, 0, 0, 0);
      acc2 = __builtin_amdgcn_mfma_f32_32x32x16_bf16(ah, bl, acc2, 0, 0, 0);
      acc3 = __builtin_amdgcn_mfma_f32_32x32x16_bf16(al, bh, acc3, 0, 0, 0);
    }
    __syncthreads();
    #pragma unroll
    for (int r = 0; r < 16; ++r) {
      int m = mt*32 + (r&3) + 8*(r>>2) + 4*h;
      float x = acc1[r] + acc2[r] + acc3[r];
      float xpu = x + u[r];
      float zz = fminf(fmaxf(xpu, 0.f), 1.f);
      u[r] = xpu - zz;
      z[r] = zz;
      float rhs = zz - u[r] - pr[r];
      unsigned short hh = f2bf(rhs);
      unsigned short ll = f2bf(rhs - bf2f(hh));
      int idx = ((m >> 3)*32 + n_l)*8 + (m & 7);
      Bhi[idx] = hh; Blo[idx] = ll;
    }
    __syncthreads();
  }

  float s = 0.f;
  #pragma unroll
  for (int r = 0; r < 16; ++r) {
    int m = mt*32 + (r&3) + 8*(r>>2) + 4*h;
    if (m < NP) s += z[r];
  }
  s += __shfl_xor(s, 32, 64);
  if (l < 32) ssum[wv][n_l] = s;
  __syncthreads();
  float stot = 0.f;
  #pragma unroll
  for (int q = 0; q < 7; ++q) stot += ssum[q][n_l];
  float inv = (n < NP) ? 1.f/(stot + 1e-10f) : 0.f;
  #pragma unroll
  for (int r = 0; r < 16; ++r) {
    float c = z[r] * inv * (1.f/196.f);
    #pragma unroll
    for (int o = 16; o; o >>= 1) c += __shfl_xor(c, o, 64);
    if (n_l == 0) {
      int m = mt*32 + (r&3) + 8*(r>>2) + 4*h;
      if (m < NP) atomicAdd(&w[b*NP + m], c);
    }
  }
}

// ---------------- fused pooled + LN + head + softmax ----------------
__global__ __launch_bounds__(256) void k_finish(
    const float* __restrict__ w, const float* __restrict__ V,
    const float* __restrict__ g, const float* __restrict__ be,
    const float* __restrict__ Wm, const float* __restrict__ bm,
    float* __restrict__ out) {
  int b = blockIdx.x, t = threadIdx.x;
  __shared__ float ws_[NP];
  __shared__ float pl[512];
  __shared__ float rb[8];
  if (t < NP) ws_[t] = w[b*NP + t];
  __syncthreads();
  const float* Vb = V + (size_t)b*NP*512;
  float a0 = 0.f, a1 = 0.f;
  #pragma unroll 4
  for (int m = 0; m < NP; ++m) {
    float wm = ws_[m];
    a0 = fmaf(wm, Vb[(size_t)m*512 + t], a0);
    a1 = fmaf(wm, Vb[(size_t)m*512 + 256 + t], a1);
  }
  float s = a0+a1, ss = a0*a0+a1*a1;
  for (int o = 32; o; o >>= 1) { s += __shfl_down(s,o); ss += __shfl_down(ss,o); }
  if ((t&63)==0) { rb[t>>6]=s; rb[4+(t>>6)]=ss; }
  __syncthreads();
  float S = rb[0]+rb[1]+rb[2]+rb[3], SS = rb[4]+rb[5]+rb[6]+rb[7];
  float mu = S*(1.f/512.f), var = SS*(1.f/512.f)-mu*mu, inv = rsqrtf(var+1e-5f);
  pl[t]     = (a0-mu)*inv*g[t] + be[t];
  pl[t+256] = (a1-mu)*inv*g[t+256] + be[t+256];
  __syncthreads();
  float lg[4];
  #pragma unroll
  for (int qq = 0; qq < 4; ++qq) {
    int c = t + (qq<<8);
    float a = -1e30f;
    if (c < NC) {
      a = bm[c];
      #pragma unroll 8
      for (int k = 0; k < 512; ++k) a += pl[k]*Wm[(size_t)k*NC + c];
    }
    lg[qq] = a;
  }
  float mx = fmaxf(fmaxf(lg[0],lg[1]), fmaxf(lg[2],lg[3]));
  for (int o = 32; o; o >>= 1) mx = fmaxf(mx, __shfl_down(mx,o));
  __syncthreads();
  if ((t&63)==0) rb[t>>6] = mx;
  __syncthreads();
  float MX = fmaxf(fmaxf(rb[0],rb[1]), fmaxf(rb[2],rb[3]));
  float es = 0.f, ev[4];
  #pragma unroll
  for (int qq = 0; qq < 4; ++qq) {
    int c = t + (qq<<8);
    ev[qq] = (c < NC) ? __expf(lg[qq]-MX) : 0.f;
    es += ev[qq];
  }
  for (int o = 32; o; o >>= 1) es += __shfl_down(es,o);
  __syncthreads();
  if ((t&63)==0) rb[4+(t>>6)] = es;
  __syncthreads();
  float SUM = rb[4]+rb[5]+rb[6]+rb[7];
  float rinv = 1.f/SUM;
  #pragma unroll
  for (int qq = 0; qq < 4; ++qq) {
    int c = t + (qq<<8);
    if (c < NC) out[(size_t)b*NC + c] = ev[qq]*rinv;
  }
}

extern "C" void kernel_launch(void* const* d_in, const int* in_sizes, int n_in,
                              void* d_out, int out_size, void* d_ws, size_t ws_size,
                              hipStream_t stream) {
  const float* img = (const float*)d_in[0];
  const float* lpg = (const float*)d_in[1];
  const float* lpb = (const float*)d_in[2];
  const float* wqw = (const float*)d_in[3];
  const float* wqb = (const float*)d_in[4];
  const float* lqg = (const float*)d_in[5];
  const float* lqb = (const float*)d_in[6];
  const float* wvw = (const float*)d_in[7];
  const float* wvb = (const float*)d_in[8];
  const float* lvg = (const float*)d_in[9];
  const float* lvb = (const float*)d_in[10];
  const float* pos = (const float*)d_in[11];
  const float* mlg = (const float*)d_in[12];
  const float* mlb = (const float*)d_in[13];
  const float* mw  = (const float*)d_in[14];
  const float* mb  = (const float*)d_in[15];
  float* outp = (float*)d_out;

  float* ws = (float*)d_ws;
  size_t off = 0;
  float* q  = ws + off;      off += (size_t)B_*NP*DM;
  float* v  = ws + off;      off += (size_t)B_*NP*DM;
  size_t matp = (size_t)B_*MAT + 256;
  float* A  = ws + off;      off += matp;
  float* p  = ws + off;      off += matp;
  float* Xa = ws + off;      off += matp;
  float* Xb = ws + off;      off += matp;
  float* Ya = ws + off;      off += matp;
  float* Yb = A;                            // alias: A dead after k_nsinit2
  float* w  = ws + off;      off += (size_t)B_*NP;
  off = (off + 3) & ~(size_t)3;             // 16B align for short8 loads
  size_t swzE = (size_t)B_*7*13*512;        // Minv frag ushorts per component
  unsigned short* Ahi = (unsigned short*)(ws + off); off += swzE/2;
  unsigned short* Alo = (unsigned short*)(ws + off); off += swzE/2;
  size_t xfE = (size_t)196*48*512;          // X frag ushorts per component
  unsigned short* Xfh = (unsigned short*)(ws + off); off += xfE/2;
  unsigned short* Xfl = (unsigned short*)(ws + off); off += xfE/2;
  size_t wfE = (size_t)16*48*512;           // W frag ushorts per component
  unsigned short* Wqh = (unsigned short*)(ws + off); off += wfE/2;
  unsigned short* Wql = (unsigned short*)(ws + off); off += wfE/2;
  unsigned short* Wvh = (unsigned short*)(ws + off); off += wfE/2;
  unsigned short* Wvl = (unsigned short*)(ws + off); off += wfE/2;
  if (ws_size < off * sizeof(float)) return;

  k_wswz<<<dim3(768), 256, 0, stream>>>(wqw, Wqh, Wql);
  k_wswz<<<dim3(768), 256, 0, stream>>>(wvw, Wvh, Wvl);
  k_patchify<<<dim3(B_*NP), 256, 0, stream>>>(img, lpg, lpb, pos, Xfh, Xfl);
  k_qv_mfma<<<dim3(196, 2), 256, 0, stream>>>(Xfh, Xfl, Wqh, Wql, Wvh, Wvl,
                                              wqb, wvb, q, v);
  k_ln2<<<dim3(2*B_*NP), 256, 0, stream>>>(q, v, lqg, lqb, lvg, lvb);
  k_gram<<<dim3(4,4,64), 256, 0, stream>>>(q, v, A, p);
  k_nsinit2<<<dim3(B_), 256, 0, stream>>>(A, Xa, Ya);
  k_ns<<<dim3(4,4,64), 256, 0, stream>>>(Xa, Ya, Xb, Yb);
  k_ns<<<dim3(4,4,64), 256, 0, stream>>>(Xb, Yb, Xa, Ya);
  k_ns<<<dim3(4,4,64), 256, 0, stream>>>(Xa, Ya, Xb, Yb);
  k_swz<<<dim3(B_*7), 256, 0, stream>>>(Xb, Ahi, Alo);
  (void)hipMemsetAsync(w, 0, (size_t)B_*NP*sizeof(float), stream);
  k_admm7<<<dim3(7*B_), 448, 0, stream>>>(Ahi, Alo, p, w);
  k_finish<<<dim3(B_), 256, 0, stream>>>(w, v, mlg, mlb, mw, mb, outp);
}

// Round 10
// 574.835 us; speedup vs baseline: 18.9379x; 1.1411x over previous
//
#include <hip/hip_runtime.h>

#define B_ 32
#define NP 196
#define PD 768
#define DM 512
#define NC 1000
#define MAT (NP*NP)

typedef __attribute__((ext_vector_type(8))) short short8;
typedef __attribute__((ext_vector_type(16))) float f32x16;

__device__ inline unsigned short f2bf(float x) {
  union { float f; unsigned u; } c; c.f = x;
  unsigned r = c.u + 0x7FFFu + ((c.u >> 16) & 1u);
  return (unsigned short)(r >> 16);
}
__device__ inline float bf2f(unsigned short h) {
  union { unsigned u; float f; } c; c.u = ((unsigned)h) << 16; return c.f;
}

// ---------------- patchify + LN + pos -> X in A-fragment hi/lo bf16 layout ----------------
__global__ __launch_bounds__(256) void k_patchify(
    const float* __restrict__ img, const float* __restrict__ g,
    const float* __restrict__ be, const float* __restrict__ pos,
    unsigned short* __restrict__ Xh, unsigned short* __restrict__ Xl) {
  int bn = blockIdx.x;
  int b = bn / NP, n = bn % NP;
  int gh = n / 14, gw = n % 14;
  int t = threadIdx.x;
  float vals[3]; float s = 0.f, ss = 0.f;
  #pragma unroll
  for (int k = 0; k < 3; ++k) {
    int e = t + (k << 8);
    int inner = e & 255;
    int ph = inner >> 4, pw = inner & 15;
    float v = img[((b*3 + k)*224 + gh*16 + ph)*224 + gw*16 + pw];
    vals[k] = v; s += v; ss += v*v;
  }
  __shared__ float rb[8];
  for (int o = 32; o; o >>= 1) { s += __shfl_down(s,o); ss += __shfl_down(ss,o); }
  if ((t & 63) == 0) { rb[t>>6] = s; rb[4+(t>>6)] = ss; }
  __syncthreads();
  float S = rb[0]+rb[1]+rb[2]+rb[3], SS = rb[4]+rb[5]+rb[6]+rb[7];
  float mu = S * (1.f/768.f);
  float var = SS * (1.f/768.f) - mu*mu;
  float inv = rsqrtf(var + 1e-5f);
  int mt = bn >> 5, ml = bn & 31;
  size_t base = (size_t)mt * 48 * 512;
  #pragma unroll
  for (int k = 0; k < 3; ++k) {
    int e = t + (k << 8);
    float val = (vals[k]-mu)*inv*g[e] + be[e] + pos[n*PD + e];
    unsigned short hh = f2bf(val);
    unsigned short ll = f2bf(val - bf2f(hh));
    int ks = e >> 4, h = (e >> 3) & 1, j = e & 7;
    size_t idx = base + ((size_t)ks*64 + ml + 32*h)*8 + j;
    Xh[idx] = hh; Xl[idx] = ll;
  }
}

// ---------------- weight -> B-fragment hi/lo bf16 layout ----------------
__global__ __launch_bounds__(256) void k_wswz(
    const float* __restrict__ W,
    unsigned short* __restrict__ Bh, unsigned short* __restrict__ Bl) {
  int k = blockIdx.x;           // 0..767
  int t = threadIdx.x;
  int ks = k >> 4, h = (k >> 3) & 1, j = k & 7;
  #pragma unroll
  for (int q = 0; q < 2; ++q) {
    int n = t + (q << 8);
    float v = W[(size_t)k*512 + n];
    unsigned short hh = f2bf(v);
    unsigned short ll = f2bf(v - bf2f(hh));
    size_t idx = (((size_t)(n>>5)*48 + ks)*64 + (n&31) + 32*h)*8 + j;
    Bh[idx] = hh; Bl[idx] = ll;
  }
}

// ---------------- Q/V projection via bf16-split MFMA (no LDS, frags from L2/L3) ----------
__global__ __launch_bounds__(256, 1) void k_qv_mfma(
    const unsigned short* __restrict__ Xh, const unsigned short* __restrict__ Xl,
    const unsigned short* __restrict__ Wqh, const unsigned short* __restrict__ Wql,
    const unsigned short* __restrict__ Wvh, const unsigned short* __restrict__ Wvl,
    const float* __restrict__ bq, const float* __restrict__ bv,
    float* __restrict__ qo, float* __restrict__ vo) {
  int mt = blockIdx.x, proj = blockIdx.y;
  const unsigned short* Bh = proj ? Wvh : Wqh;
  const unsigned short* Bl = proj ? Wvl : Wql;
  const float* bias = proj ? bv : bq;
  float* out = proj ? vo : qo;
  int t = threadIdx.x, wv = t >> 6, l = t & 63;
  int n_l = l & 31, h = l >> 5;
  const unsigned short* ah_p = Xh + (size_t)mt*48*512 + l*8;
  const unsigned short* al_p = Xl + (size_t)mt*48*512 + l*8;
  f32x16 acc1[4], acc2[4];
  #pragma unroll
  for (int q4 = 0; q4 < 4; ++q4)
    #pragma unroll
    for (int i = 0; i < 16; ++i) { acc1[q4][i] = 0.f; acc2[q4][i] = 0.f; }
  #pragma unroll 2
  for (int ks = 0; ks < 48; ++ks) {
    short8 ah = *reinterpret_cast<const short8*>(ah_p + (size_t)ks*512);
    short8 al = *reinterpret_cast<const short8*>(al_p + (size_t)ks*512);
    #pragma unroll
    for (int q4 = 0; q4 < 4; ++q4) {
      int nt = wv*4 + q4;
      size_t bo = ((size_t)nt*48 + ks)*512 + l*8;
      short8 bh = *reinterpret_cast<const short8*>(Bh + bo);
      short8 bl8 = *reinterpret_cast<const short8*>(Bl + bo);
      acc1[q4] = __builtin_amdgcn_mfma_f32_32x32x16_bf16(ah, bh,  acc1[q4], 0, 0, 0);
      acc2[q4] = __builtin_amdgcn_mfma_f32_32x32x16_bf16(ah, bl8, acc2[q4], 0, 0, 0);
      acc2[q4] = __builtin_amdgcn_mfma_f32_32x32x16_bf16(al, bh,  acc2[q4], 0, 0, 0);
    }
  }
  #pragma unroll
  for (int q4 = 0; q4 < 4; ++q4) {
    int nt = wv*4 + q4;
    float bb = bias[nt*32 + n_l];
    #pragma unroll
    for (int r = 0; r < 16; ++r) {
      int rl = (r&3) + 8*(r>>2) + 4*h;
      out[(size_t)(mt*32 + rl)*512 + nt*32 + n_l] = acc1[q4][r] + acc2[q4][r] + bb;
    }
  }
}

// ---------------- merged row LayerNorm for q (scale 1) and v (scale 1/196) ----------------
__global__ __launch_bounds__(256) void k_ln2(
    float* __restrict__ q, float* __restrict__ v,
    const float* __restrict__ gq, const float* __restrict__ bq,
    const float* __restrict__ gv, const float* __restrict__ bv) {
  int r = blockIdx.x; bool hv = (r >= B_*NP); if (hv) r -= B_*NP;
  float* X = hv ? v : q;
  const float* g  = hv ? gv : gq;
  const float* be = hv ? bv : bq;
  float scale = hv ? (1.f/196.f) : 1.f;
  int t = threadIdx.x;
  float v0 = X[(size_t)r*512 + t], v1 = X[(size_t)r*512 + 256 + t];
  float s = v0+v1, ss = v0*v0+v1*v1;
  __shared__ float rb[8];
  for (int o = 32; o; o >>= 1) { s += __shfl_down(s,o); ss += __shfl_down(ss,o); }
  if ((t&63)==0) { rb[t>>6]=s; rb[4+(t>>6)]=ss; }
  __syncthreads();
  float S = rb[0]+rb[1]+rb[2]+rb[3], SS = rb[4]+rb[5]+rb[6]+rb[7];
  float mu = S*(1.f/512.f), var = SS*(1.f/512.f)-mu*mu;
  float inv = rsqrtf(var+1e-5f);
  X[(size_t)r*512+t]     = ((v0-mu)*inv*g[t]+be[t])*scale;
  X[(size_t)r*512+256+t] = ((v1-mu)*inv*g[t+256]+be[t+256])*scale;
}

// ---------------- merged Gram: z<32: A=2VV^T+I ; z>=32: p=-2QV^T+1/196 ----------------
__global__ __launch_bounds__(256) void k_gram(
    const float* __restrict__ q, const float* __restrict__ v,
    float* __restrict__ Ao, float* __restrict__ po) {
  int zz = blockIdx.z; int b = zz & 31; bool hp = (zz >= 32);
  float alpha  = hp ? -2.f : 2.f;
  float diagAdd = hp ? 0.f : 1.f;
  float cAdd   = hp ? (1.f/196.f) : 0.f;
  const float* Xb = (hp ? q : v) + (size_t)b*NP*512;
  const float* Yb = v + (size_t)b*NP*512;
  float* out = (hp ? po : Ao) + (size_t)b*MAT;
  int c0 = blockIdx.x * 64, r0 = blockIdx.y * 64;
  __shared__ __align__(16) float Xs[16][68];
  __shared__ __align__(16) float Ys[16][68];
  int t = threadIdx.x, tx = t & 15, ty = t >> 4;
  int lr = t >> 2, lc4 = (t & 3) << 2;
  float acc[4][4] = {};
  int xr = min(r0 + lr, NP-1), yr = min(c0 + lr, NP-1);
  for (int k0 = 0; k0 < 512; k0 += 16) {
    float4 xv = *reinterpret_cast<const float4*>(&Xb[(size_t)xr*512 + k0 + lc4]);
    float4 yv = *reinterpret_cast<const float4*>(&Yb[(size_t)yr*512 + k0 + lc4]);
    Xs[lc4+0][lr] = xv.x; Xs[lc4+1][lr] = xv.y;
    Xs[lc4+2][lr] = xv.z; Xs[lc4+3][lr] = xv.w;
    Ys[lc4+0][lr] = yv.x; Ys[lc4+1][lr] = yv.y;
    Ys[lc4+2][lr] = yv.z; Ys[lc4+3][lr] = yv.w;
    __syncthreads();
    #pragma unroll
    for (int kt = 0; kt < 16; ++kt) {
      float a4[4], b4[4];
      *reinterpret_cast<float4*>(a4) = *reinterpret_cast<const float4*>(&Xs[kt][ty<<2]);
      *reinterpret_cast<float4*>(b4) = *reinterpret_cast<const float4*>(&Ys[kt][tx<<2]);
      #pragma unroll
      for (int i = 0; i < 4; ++i)
        #pragma unroll
        for (int j = 0; j < 4; ++j) acc[i][j] += a4[i]*b4[j];
    }
    __syncthreads();
  }
  #pragma unroll
  for (int i = 0; i < 4; ++i) {
    int r = r0 + (ty<<2) + i; if (r >= NP) continue;
    #pragma unroll
    for (int j = 0; j < 4; ++j) {
      int c = c0 + (tx<<2) + j; if (c >= NP) continue;
      out[(size_t)r*NP + c] = alpha*acc[i][j] + cAdd + (r==c ? diagAdd : 0.f);
    }
  }
}

// ---------------- NS init: ninf bound, X0 = c*I, Y0 = c*A (Y tracks A@X) ----------------
__global__ __launch_bounds__(256) void k_nsinit2(
    const float* __restrict__ A, float* __restrict__ X, float* __restrict__ Y) {
  int b = blockIdx.x, t = threadIdx.x;
  const float* Ab = A + (size_t)b*MAT;
  __shared__ float sm[256];
  float lm = 0.f;
  if (t < NP) {
    float s = 0.f;
    for (int j = 0; j < NP; ++j) {
      float v = Ab[t*NP + j];
      if (j == t) v -= 1.f;
      s += fabsf(v);
    }
    lm = s;
  }
  sm[t] = lm; __syncthreads();
  for (int o = 128; o; o >>= 1) { if (t < o) sm[t] = fmaxf(sm[t], sm[t+o]); __syncthreads(); }
  float cc = 2.f / (2.f + sm[0]);
  float* Xb = X + (size_t)b*MAT;
  float* Yb = Y + (size_t)b*MAT;
  for (int idx = t; idx < MAT; idx += 256) {
    Xb[idx] = (idx % (NP+1) == 0) ? cc : 0.f;
    Yb[idx] = cc * Ab[idx];
  }
}

// ---------------- NS iter: z<32: Xn=2X-X@Y ; z>=32: Yn=2Y-Y@Y ----------------
__global__ __launch_bounds__(256) void k_ns(
    const float* __restrict__ X, const float* __restrict__ Y,
    float* __restrict__ Xn, float* __restrict__ Yn) {
  int zz = blockIdx.z; int b = zz & 31; bool hy = (zz >= 32);
  const float* Lb = (hy ? Y : X) + (size_t)b*MAT;
  const float* Rb = Y + (size_t)b*MAT;
  float* Ob = (hy ? Yn : Xn) + (size_t)b*MAT;
  int c0 = blockIdx.x * 64, r0 = blockIdx.y * 64;
  __shared__ __align__(16) float Ls[16][68];
  __shared__ __align__(16) float Rs[16][64];
  int t = threadIdx.x, tx = t & 15, ty = t >> 4;
  int alr = t >> 2, alc = (t & 3) << 2;
  int blr = t >> 4, blc = (t & 15) << 2;
  float acc[4][4] = {};
  int lrow = min(r0 + alr, NP-1);
  for (int k0 = 0; k0 < NP; k0 += 16) {
    float4 lv = {0.f,0.f,0.f,0.f};
    if (k0 + alc < NP) lv = *reinterpret_cast<const float4*>(&Lb[(size_t)lrow*NP + k0 + alc]);
    float4 rv = {0.f,0.f,0.f,0.f};
    if (k0 + blr < NP) rv = *reinterpret_cast<const float4*>(&Rb[(size_t)(k0+blr)*NP + c0 + blc]);
    Ls[alc+0][alr] = lv.x; Ls[alc+1][alr] = lv.y;
    Ls[alc+2][alr] = lv.z; Ls[alc+3][alr] = lv.w;
    *reinterpret_cast<float4*>(&Rs[blr][blc]) = rv;
    __syncthreads();
    #pragma unroll
    for (int kt = 0; kt < 16; ++kt) {
      float a4[4], b4[4];
      *reinterpret_cast<float4*>(a4) = *reinterpret_cast<const float4*>(&Ls[kt][ty<<2]);
      *reinterpret_cast<float4*>(b4) = *reinterpret_cast<const float4*>(&Rs[kt][tx<<2]);
      #pragma unroll
      for (int i = 0; i < 4; ++i)
        #pragma unroll
        for (int j = 0; j < 4; ++j) acc[i][j] += a4[i]*b4[j];
    }
    __syncthreads();
  }
  #pragma unroll
  for (int i = 0; i < 4; ++i) {
    int r = r0 + (ty<<2) + i; if (r >= NP) continue;
    #pragma unroll
    for (int j = 0; j < 4; ++j) {
      int c = c0 + (tx<<2) + j; if (c >= NP) continue;
      Ob[(size_t)r*NP + c] = 2.f*Lb[(size_t)r*NP + c] - acc[i][j];
    }
  }
}

// ---------------- Minv -> bf16 hi/lo split, pre-swizzled into MFMA A-fragment order ----
__global__ __launch_bounds__(256) void k_swz(
    const float* __restrict__ Minv,
    unsigned short* __restrict__ Ahi, unsigned short* __restrict__ Alo) {
  int bid = blockIdx.x;          // 32*7
  int b = bid & 31, mt = bid >> 5;
  int t = threadIdx.x;
  int l = t & 63, jp = (t >> 6) * 2;
  int m = mt*32 + (l & 31);
  const float* Mb = Minv + (size_t)b*MAT;
  size_t obase = ((size_t)(b*7 + mt)*13)*512;
  for (int ks = 0; ks < 13; ++ks) {
    #pragma unroll
    for (int jo = 0; jo < 2; ++jo) {
      int j = jp + jo;
      int k = ks*16 + (l>>5)*8 + j;
      float v = (m < NP && k < NP) ? Mb[(size_t)m*NP + k] : 0.f;
      unsigned short hh = f2bf(v);
      unsigned short ll = f2bf(v - bf2f(hh));
      size_t idx = obase + (size_t)ks*512 + l*8 + j;
      Ahi[idx] = hh; Alo[idx] = ll;
    }
  }
}

// ---------------- fused 50-iter ADMM: bf16-split MFMA ----------------
__global__ __launch_bounds__(448) void k_admm7(
    const unsigned short* __restrict__ Ahi, const unsigned short* __restrict__ Alo,
    const float* __restrict__ P, float* __restrict__ w) {
  int bid = blockIdx.x;
  int b = bid & 31, tt = bid >> 5;
  int t = threadIdx.x;
  int wv = t >> 6;
  int l = t & 63;
  int n_l = l & 31, h = l >> 5;
  int n = tt*32 + n_l;
  int mt = wv;

  __shared__ __align__(16) unsigned short Bhi[26*32*8];
  __shared__ __align__(16) unsigned short Blo[26*32*8];
  __shared__ float ssum[7][32];

  float z[16], u[16], pr[16];
  int ngc = min(n, NP-1);
  const float* prow = P + ((size_t)b*NP + ngc)*NP;
  #pragma unroll
  for (int r = 0; r < 16; ++r) {
    int m = mt*32 + (r&3) + 8*(r>>2) + 4*h;
    pr[r] = prow[min(m, NP-1)];
    z[r] = 0.f; u[r] = 0.f;
  }
  #pragma unroll
  for (int r = 0; r < 16; ++r) {
    int m = mt*32 + (r&3) + 8*(r>>2) + 4*h;
    float rhs = -pr[r];
    unsigned short hh = f2bf(rhs);
    unsigned short ll = f2bf(rhs - bf2f(hh));
    int idx = ((m >> 3)*32 + n_l)*8 + (m & 7);
    Bhi[idx] = hh; Blo[idx] = ll;
  }
  __syncthreads();

  const unsigned short* ah_base = Ahi + ((size_t)(b*7 + mt)*13)*512 + l*8;
  const unsigned short* al_base = Alo + ((size_t)(b*7 + mt)*13)*512 + l*8;
  int boff = (h*32 + n_l)*8;

  for (int it = 0; it < 50; ++it) {
    f32x16 acc1, acc2, acc3;
    #pragma unroll
    for (int i = 0; i < 16; ++i) { acc1[i] = 0.f; acc2[i] = 0.f; acc3[i] = 0.f; }
    #pragma unroll
    for (int ks = 0; ks < 13; ++ks) {
      short8 ah = *reinterpret_cast<const short8*>(ah_base + (size_t)ks*512);
      short8 al = *reinterpret_cast<const short8*>(al_base + (size_t)ks*512);
      short8 bh = *reinterpret_cast<const short8*>(&Bhi[ks*512 + boff]);
      short8 bl = *reinterpret_cast<const short8*>(&Blo[ks*512 + boff]);
      acc1 = __builtin_amdgcn_mfma_f32_32x32x16_bf16(ah, bh, acc1, 0, 0, 0);
      acc2 = __builtin_amdgcn_mfma_f32_32x32x16_bf16(ah, bl, acc2, 0, 0, 0);
      acc3 = __builtin_amdgcn_mfma_f32_32x32x16_bf16(al, bh, acc3, 0, 0, 0);
    }
    __syncthreads();
    #pragma unroll
    for (int r = 0; r < 16; ++r) {
      int m = mt*32 + (r&3) + 8*(r>>2) + 4*h;
      float x = acc1[r] + acc2[r] + acc3[r];
      float xpu = x + u[r];
      float zz = fminf(fmaxf(xpu, 0.f), 1.f);
      u[r] = xpu - zz;
      z[r] = zz;
      float rhs = zz - u[r] - pr[r];
      unsigned short hh = f2bf(rhs);
      unsigned short ll = f2bf(rhs - bf2f(hh));
      int idx = ((m >> 3)*32 + n_l)*8 + (m & 7);
      Bhi[idx] = hh; Blo[idx] = ll;
    }
    __syncthreads();
  }

  float s = 0.f;
  #pragma unroll
  for (int r = 0; r < 16; ++r) {
    int m = mt*32 + (r&3) + 8*(r>>2) + 4*h;
    if (m < NP) s += z[r];
  }
  s += __shfl_xor(s, 32, 64);
  if (l < 32) ssum[wv][n_l] = s;
  __syncthreads();
  float stot = 0.f;
  #pragma unroll
  for (int q = 0; q < 7; ++q) stot += ssum[q][n_l];
  float inv = (n < NP) ? 1.f/(stot + 1e-10f) : 0.f;
  #pragma unroll
  for (int r = 0; r < 16; ++r) {
    float c = z[r] * inv * (1.f/196.f);
    #pragma unroll
    for (int o = 16; o; o >>= 1) c += __shfl_xor(c, o, 64);
    if (n_l == 0) {
      int m = mt*32 + (r&3) + 8*(r>>2) + 4*h;
      if (m < NP) atomicAdd(&w[b*NP + m], c);
    }
  }
}

// ---------------- pooled + LN -> pl_g[b][512] ----------------
__global__ __launch_bounds__(256) void k_pool(
    const float* __restrict__ w, const float* __restrict__ V,
    const float* __restrict__ g, const float* __restrict__ be,
    float* __restrict__ pl_g) {
  int b = blockIdx.x, t = threadIdx.x;
  __shared__ float ws_[NP];
  __shared__ float rb[8];
  if (t < NP) ws_[t] = w[b*NP + t];
  __syncthreads();
  const float* Vb = V + (size_t)b*NP*512;
  float a0 = 0.f, a1 = 0.f;
  #pragma unroll 4
  for (int m = 0; m < NP; ++m) {
    float wm = ws_[m];
    a0 = fmaf(wm, Vb[(size_t)m*512 + t], a0);
    a1 = fmaf(wm, Vb[(size_t)m*512 + 256 + t], a1);
  }
  float s = a0+a1, ss = a0*a0+a1*a1;
  for (int o = 32; o; o >>= 1) { s += __shfl_down(s,o); ss += __shfl_down(ss,o); }
  if ((t&63)==0) { rb[t>>6]=s; rb[4+(t>>6)]=ss; }
  __syncthreads();
  float S = rb[0]+rb[1]+rb[2]+rb[3], SS = rb[4]+rb[5]+rb[6]+rb[7];
  float mu = S*(1.f/512.f), var = SS*(1.f/512.f)-mu*mu, inv = rsqrtf(var+1e-5f);
  pl_g[(size_t)b*512 + t]       = (a0-mu)*inv*g[t] + be[t];
  pl_g[(size_t)b*512 + 256 + t] = (a1-mu)*inv*g[t+256] + be[t+256];
}

// ---------------- head GEMM: 256 blocks (8 col-groups x 32 batches), k-split 4 ----------
__global__ __launch_bounds__(512) void k_head(
    const float* __restrict__ pl_g, const float* __restrict__ Wm,
    const float* __restrict__ bm, float* __restrict__ logits) {
  int cg = blockIdx.x, b = blockIdx.y;
  int t = threadIdx.x;
  int c0 = cg * 125;
  __shared__ float pl[512];
  __shared__ float part[4][128];
  pl[t] = pl_g[(size_t)b*512 + t];
  __syncthreads();
  int kk = t >> 7, cc = t & 127;
  float a = 0.f;
  if (cc < 125) {
    int c = c0 + cc;
    const float* wp = Wm + (size_t)(kk*128)*NC + c;
    #pragma unroll 8
    for (int k = 0; k < 128; ++k) a = fmaf(pl[kk*128 + k], wp[(size_t)k*NC], a);
  }
  part[kk][cc] = a;
  __syncthreads();
  if (t < 125) {
    float lg = part[0][t] + part[1][t] + part[2][t] + part[3][t] + bm[c0 + t];
    logits[(size_t)b*NC + c0 + t] = lg;
  }
}

// ---------------- softmax over 1000 ----------------
__global__ __launch_bounds__(256) void k_soft(
    const float* __restrict__ logits, float* __restrict__ out) {
  int b = blockIdx.x, t = threadIdx.x;
  __shared__ float rb[8];
  float lg[4];
  #pragma unroll
  for (int q = 0; q < 4; ++q) {
    int c = t + (q<<8);
    lg[q] = (c < NC) ? logits[(size_t)b*NC + c] : -1e30f;
  }
  float mx = fmaxf(fmaxf(lg[0],lg[1]), fmaxf(lg[2],lg[3]));
  for (int o = 32; o; o >>= 1) mx = fmaxf(mx, __shfl_down(mx,o));
  if ((t&63)==0) rb[t>>6] = mx;
  __syncthreads();
  float MX = fmaxf(fmaxf(rb[0],rb[1]), fmaxf(rb[2],rb[3]));
  float es = 0.f, ev[4];
  #pragma unroll
  for (int q = 0; q < 4; ++q) {
    int c = t + (q<<8);
    ev[q] = (c < NC) ? __expf(lg[q]-MX) : 0.f;
    es += ev[q];
  }
  for (int o = 32; o; o >>= 1) es += __shfl_down(es,o);
  __syncthreads();
  if ((t&63)==0) rb[4+(t>>6)] = es;
  __syncthreads();
  float SUM = rb[4]+rb[5]+rb[6]+rb[7];
  float rinv = 1.f/SUM;
  #pragma unroll
  for (int q = 0; q < 4; ++q) {
    int c = t + (q<<8);
    if (c < NC) out[(size_t)b*NC + c] = ev[q]*rinv;
  }
}

extern "C" void kernel_launch(void* const* d_in, const int* in_sizes, int n_in,
                              void* d_out, int out_size, void* d_ws, size_t ws_size,
                              hipStream_t stream) {
  const float* img = (const float*)d_in[0];
  const float* lpg = (const float*)d_in[1];
  const float* lpb = (const float*)d_in[2];
  const float* wqw = (const float*)d_in[3];
  const float* wqb = (const float*)d_in[4];
  const float* lqg = (const float*)d_in[5];
  const float* lqb = (const float*)d_in[6];
  const float* wvw = (const float*)d_in[7];
  const float* wvb = (const float*)d_in[8];
  const float* lvg = (const float*)d_in[9];
  const float* lvb = (const float*)d_in[10];
  const float* pos = (const float*)d_in[11];
  const float* mlg = (const float*)d_in[12];
  const float* mlb = (const float*)d_in[13];
  const float* mw  = (const float*)d_in[14];
  const float* mb  = (const float*)d_in[15];
  float* outp = (float*)d_out;

  float* ws = (float*)d_ws;
  size_t off = 0;
  float* q  = ws + off;      off += (size_t)B_*NP*DM;
  float* v  = ws + off;      off += (size_t)B_*NP*DM;
  size_t matp = (size_t)B_*MAT + 256;
  float* A  = ws + off;      off += matp;
  float* p  = ws + off;      off += matp;
  float* Xa = ws + off;      off += matp;
  float* Xb = ws + off;      off += matp;
  float* Ya = ws + off;      off += matp;
  float* Yb = A;                            // alias: A dead after k_nsinit2
  float* w  = ws + off;      off += (size_t)B_*NP;
  float* pl_g = ws + off;    off += (size_t)B_*DM;
  float* logits = ws + off;  off += (size_t)B_*NC;
  off = (off + 3) & ~(size_t)3;             // 16B align for short8 loads
  size_t swzE = (size_t)B_*7*13*512;        // Minv frag ushorts per component
  unsigned short* Ahi = (unsigned short*)(ws + off); off += swzE/2;
  unsigned short* Alo = (unsigned short*)(ws + off); off += swzE/2;
  size_t xfE = (size_t)196*48*512;          // X frag ushorts per component
  unsigned short* Xfh = (unsigned short*)(ws + off); off += xfE/2;
  unsigned short* Xfl = (unsigned short*)(ws + off); off += xfE/2;
  size_t wfE = (size_t)16*48*512;           // W frag ushorts per component
  unsigned short* Wqh = (unsigned short*)(ws + off); off += wfE/2;
  unsigned short* Wql = (unsigned short*)(ws + off); off += wfE/2;
  unsigned short* Wvh = (unsigned short*)(ws + off); off += wfE/2;
  unsigned short* Wvl = (unsigned short*)(ws + off); off += wfE/2;
  if (ws_size < off * sizeof(float)) return;

  k_wswz<<<dim3(768), 256, 0, stream>>>(wqw, Wqh, Wql);
  k_wswz<<<dim3(768), 256, 0, stream>>>(wvw, Wvh, Wvl);
  k_patchify<<<dim3(B_*NP), 256, 0, stream>>>(img, lpg, lpb, pos, Xfh, Xfl);
  k_qv_mfma<<<dim3(196, 2), 256, 0, stream>>>(Xfh, Xfl, Wqh, Wql, Wvh, Wvl,
                                              wqb, wvb, q, v);
  k_ln2<<<dim3(2*B_*NP), 256, 0, stream>>>(q, v, lqg, lqb, lvg, lvb);
  k_gram<<<dim3(4,4,64), 256, 0, stream>>>(q, v, A, p);
  k_nsinit2<<<dim3(B_), 256, 0, stream>>>(A, Xa, Ya);
  k_ns<<<dim3(4,4,64), 256, 0, stream>>>(Xa, Ya, Xb, Yb);
  k_ns<<<dim3(4,4,64), 256, 0, stream>>>(Xb, Yb, Xa, Ya);
  k_ns<<<dim3(4,4,64), 256, 0, stream>>>(Xa, Ya, Xb, Yb);
  k_swz<<<dim3(B_*7), 256, 0, stream>>>(Xb, Ahi, Alo);
  (void)hipMemsetAsync(w, 0, (size_t)B_*NP*sizeof(float), stream);
  k_admm7<<<dim3(7*B_), 448, 0, stream>>>(Ahi, Alo, p, w);
  k_pool<<<dim3(B_), 256, 0, stream>>>(w, v, mlg, mlb, pl_g);
  k_head<<<dim3(8, B_), 512, 0, stream>>>(pl_g, mw, mb, logits);
  k_soft<<<dim3(B_), 256, 0, stream>>>(logits, outp);
}

// Round 11
// 567.145 us; speedup vs baseline: 19.1947x; 1.0136x over previous
//
#include <hip/hip_runtime.h>

#define B_ 32
#define NP 196
#define PD 768
#define DM 512
#define NC 1000
#define MAT (NP*NP)

typedef __attribute__((ext_vector_type(8))) short short8;
typedef __attribute__((ext_vector_type(16))) float f32x16;

__device__ inline unsigned short f2bf(float x) {
  union { float f; unsigned u; } c; c.f = x;
  unsigned r = c.u + 0x7FFFu + ((c.u >> 16) & 1u);
  return (unsigned short)(r >> 16);
}
__device__ inline float bf2f(unsigned short h) {
  union { unsigned u; float f; } c; c.u = ((unsigned)h) << 16; return c.f;
}

// ---------------- patchify + LN + pos -> X in A-fragment hi/lo bf16 layout ----------------
__global__ __launch_bounds__(256) void k_patchify(
    const float* __restrict__ img, const float* __restrict__ g,
    const float* __restrict__ be, const float* __restrict__ pos,
    unsigned short* __restrict__ Xh, unsigned short* __restrict__ Xl) {
  int bn = blockIdx.x;
  int b = bn / NP, n = bn % NP;
  int gh = n / 14, gw = n % 14;
  int t = threadIdx.x;
  float vals[3]; float s = 0.f, ss = 0.f;
  #pragma unroll
  for (int k = 0; k < 3; ++k) {
    int e = t + (k << 8);
    int inner = e & 255;
    int ph = inner >> 4, pw = inner & 15;
    float v = img[((b*3 + k)*224 + gh*16 + ph)*224 + gw*16 + pw];
    vals[k] = v; s += v; ss += v*v;
  }
  __shared__ float rb[8];
  for (int o = 32; o; o >>= 1) { s += __shfl_down(s,o); ss += __shfl_down(ss,o); }
  if ((t & 63) == 0) { rb[t>>6] = s; rb[4+(t>>6)] = ss; }
  __syncthreads();
  float S = rb[0]+rb[1]+rb[2]+rb[3], SS = rb[4]+rb[5]+rb[6]+rb[7];
  float mu = S * (1.f/768.f);
  float var = SS * (1.f/768.f) - mu*mu;
  float inv = rsqrtf(var + 1e-5f);
  int mt = bn >> 5, ml = bn & 31;
  size_t base = (size_t)mt * 48 * 512;
  #pragma unroll
  for (int k = 0; k < 3; ++k) {
    int e = t + (k << 8);
    float val = (vals[k]-mu)*inv*g[e] + be[e] + pos[n*PD + e];
    unsigned short hh = f2bf(val);
    unsigned short ll = f2bf(val - bf2f(hh));
    int ks = e >> 4, h = (e >> 3) & 1, j = e & 7;
    size_t idx = base + ((size_t)ks*64 + ml + 32*h)*8 + j;
    Xh[idx] = hh; Xl[idx] = ll;
  }
}

// ---------------- weight -> B-fragment hi/lo bf16 layout ----------------
__global__ __launch_bounds__(256) void k_wswz(
    const float* __restrict__ W,
    unsigned short* __restrict__ Bh, unsigned short* __restrict__ Bl) {
  int k = blockIdx.x;           // 0..767
  int t = threadIdx.x;
  int ks = k >> 4, h = (k >> 3) & 1, j = k & 7;
  #pragma unroll
  for (int q = 0; q < 2; ++q) {
    int n = t + (q << 8);
    float v = W[(size_t)k*512 + n];
    unsigned short hh = f2bf(v);
    unsigned short ll = f2bf(v - bf2f(hh));
    size_t idx = (((size_t)(n>>5)*48 + ks)*64 + (n&31) + 32*h)*8 + j;
    Bh[idx] = hh; Bl[idx] = ll;
  }
}

// ---------------- Q/V projection via bf16-split MFMA ----------
// Linear grid 392: proj = bid&1, mt = bid>>1 -> XCD round-robin pins ONE
// projection's B-frags (3.1 MB < 4 MB L2) per XCD (was grid(196,2): both
// projections on every XCD -> 6.2 MB -> L3 thrash at ~10 TB/s, 126 us).
__global__ __launch_bounds__(256, 1) void k_qv_mfma(
    const unsigned short* __restrict__ Xh, const unsigned short* __restrict__ Xl,
    const unsigned short* __restrict__ Wqh, const unsigned short* __restrict__ Wql,
    const unsigned short* __restrict__ Wvh, const unsigned short* __restrict__ Wvl,
    const float* __restrict__ bq, const float* __restrict__ bv,
    float* __restrict__ qo, float* __restrict__ vo) {
  int bid = blockIdx.x;
  int proj = bid & 1, mt = bid >> 1;
  const unsigned short* Bh = proj ? Wvh : Wqh;
  const unsigned short* Bl = proj ? Wvl : Wql;
  const float* bias = proj ? bv : bq;
  float* out = proj ? vo : qo;
  int t = threadIdx.x, wv = t >> 6, l = t & 63;
  int n_l = l & 31, h = l >> 5;
  const unsigned short* ah_p = Xh + (size_t)mt*48*512 + l*8;
  const unsigned short* al_p = Xl + (size_t)mt*48*512 + l*8;
  f32x16 acc1[4], acc2[4];
  #pragma unroll
  for (int q4 = 0; q4 < 4; ++q4)
    #pragma unroll
    for (int i = 0; i < 16; ++i) { acc1[q4][i] = 0.f; acc2[q4][i] = 0.f; }
  #pragma unroll 2
  for (int ks = 0; ks < 48; ++ks) {
    short8 ah = *reinterpret_cast<const short8*>(ah_p + (size_t)ks*512);
    short8 al = *reinterpret_cast<const short8*>(al_p + (size_t)ks*512);
    #pragma unroll
    for (int q4 = 0; q4 < 4; ++q4) {
      int nt = wv*4 + q4;
      size_t bo = ((size_t)nt*48 + ks)*512 + l*8;
      short8 bh = *reinterpret_cast<const short8*>(Bh + bo);
      short8 bl8 = *reinterpret_cast<const short8*>(Bl + bo);
      acc1[q4] = __builtin_amdgcn_mfma_f32_32x32x16_bf16(ah, bh,  acc1[q4], 0, 0, 0);
      acc2[q4] = __builtin_amdgcn_mfma_f32_32x32x16_bf16(ah, bl8, acc2[q4], 0, 0, 0);
      acc2[q4] = __builtin_amdgcn_mfma_f32_32x32x16_bf16(al, bh,  acc2[q4], 0, 0, 0);
    }
  }
  #pragma unroll
  for (int q4 = 0; q4 < 4; ++q4) {
    int nt = wv*4 + q4;
    float bb = bias[nt*32 + n_l];
    #pragma unroll
    for (int r = 0; r < 16; ++r) {
      int rl = (r&3) + 8*(r>>2) + 4*h;
      out[(size_t)(mt*32 + rl)*512 + nt*32 + n_l] = acc1[q4][r] + acc2[q4][r] + bb;
    }
  }
}

// ---------------- LN for q & v + emit hi/lo A-style fragments for the Gram ----------
// q fp32 is dead after this (Gram is MFMA now); v keeps fp32 for k_pool.
// Frag layout (per batch, per matrix mat: 0=q,1=v):
//   element (tok, k) -> [(((b*2+mat)*7 + tok>>5)*32 + k>>4)*512 + ((tok&31) + 32*((k>>3)&1))*8 + (k&7)]
// Pad tokens 196..223 of mt=6 stay uninitialized -> only feed masked outputs.
__global__ __launch_bounds__(256) void k_ln2(
    const float* __restrict__ q, float* __restrict__ v,
    const float* __restrict__ gq, const float* __restrict__ bq,
    const float* __restrict__ gv, const float* __restrict__ bv,
    unsigned short* __restrict__ Fh, unsigned short* __restrict__ Fl) {
  int r = blockIdx.x; bool hv = (r >= B_*NP); if (hv) r -= B_*NP;
  const float* X = hv ? v : q;
  const float* g  = hv ? gv : gq;
  const float* be = hv ? bv : bq;
  float scale = hv ? (1.f/196.f) : 1.f;
  int t = threadIdx.x;
  float v0 = X[(size_t)r*512 + t], v1 = X[(size_t)r*512 + 256 + t];
  float s = v0+v1, ss = v0*v0+v1*v1;
  __shared__ float rb[8];
  for (int o = 32; o; o >>= 1) { s += __shfl_down(s,o); ss += __shfl_down(ss,o); }
  if ((t&63)==0) { rb[t>>6]=s; rb[4+(t>>6)]=ss; }
  __syncthreads();
  float S = rb[0]+rb[1]+rb[2]+rb[3], SS = rb[4]+rb[5]+rb[6]+rb[7];
  float mu = S*(1.f/512.f), var = SS*(1.f/512.f)-mu*mu;
  float inv = rsqrtf(var+1e-5f);
  int b = r / NP, ntok = r % NP;
  int mt = ntok >> 5, ml = ntok & 31;
  size_t fb = (((size_t)b*2 + (hv?1:0))*7 + mt) * 32 * 512;
  float val0 = ((v0-mu)*inv*g[t]+be[t])*scale;
  float val1 = ((v1-mu)*inv*g[t+256]+be[t+256])*scale;
  if (hv) {
    v[(size_t)r*512+t] = val0;
    v[(size_t)r*512+256+t] = val1;
  }
  #pragma unroll
  for (int e2 = 0; e2 < 2; ++e2) {
    int e = t + (e2 << 8);
    float val = e2 ? val1 : val0;
    unsigned short hh = f2bf(val);
    unsigned short ll = f2bf(val - bf2f(hh));
    int ks = e >> 4, h = (e >> 3) & 1, j = e & 7;
    size_t idx = fb + (size_t)ks*512 + ((size_t)ml + 32*h)*8 + j;
    Fh[idx] = hh; Fl[idx] = ll;
  }
}

// ---------------- Gram via bf16-split MFMA (NT: both operands A-style frags) ----------
// grid (49, 64): tile = (mt,nt) of 7x7; z<32: A=2VV^T+I (b=z); z>=32: p=-2QV^T+1/196.
// 64 thr = 1 wave; 32 ksteps x 3 MFMAs; pad rows/cols masked at store.
__global__ __launch_bounds__(64) void k_gram_mfma(
    const unsigned short* __restrict__ Fh, const unsigned short* __restrict__ Fl,
    float* __restrict__ Ao, float* __restrict__ po) {
  int gid = blockIdx.x;
  int mt = gid / 7, nt = gid % 7;
  int z = blockIdx.y; int b = z & 31; bool hp = (z >= 32);
  int l = threadIdx.x;
  int col = l & 31, h2 = l >> 5;
  size_t abase = (((size_t)b*2 + (hp ? 0 : 1))*7 + mt) * 32 * 512 + l*8;  // X = q (p) or v (A)
  size_t bbase = (((size_t)b*2 + 1)*7 + nt) * 32 * 512 + l*8;             // Y = v always
  f32x16 a1, a2, a3;
  #pragma unroll
  for (int i = 0; i < 16; ++i) { a1[i] = 0.f; a2[i] = 0.f; a3[i] = 0.f; }
  #pragma unroll 4
  for (int ks = 0; ks < 32; ++ks) {
    short8 ah = *reinterpret_cast<const short8*>(Fh + abase + (size_t)ks*512);
    short8 al = *reinterpret_cast<const short8*>(Fl + abase + (size_t)ks*512);
    short8 bh = *reinterpret_cast<const short8*>(Fh + bbase + (size_t)ks*512);
    short8 bl = *reinterpret_cast<const short8*>(Fl + bbase + (size_t)ks*512);
    a1 = __builtin_amdgcn_mfma_f32_32x32x16_bf16(ah, bh, a1, 0, 0, 0);
    a2 = __builtin_amdgcn_mfma_f32_32x32x16_bf16(ah, bl, a2, 0, 0, 0);
    a3 = __builtin_amdgcn_mfma_f32_32x32x16_bf16(al, bh, a3, 0, 0, 0);
  }
  float alpha  = hp ? -2.f : 2.f;
  float diagAdd = hp ? 0.f : 1.f;
  float cAdd   = hp ? (1.f/196.f) : 0.f;
  float* out = (hp ? po : Ao) + (size_t)b*MAT;
  #pragma unroll
  for (int r = 0; r < 16; ++r) {
    int m = mt*32 + (r&3) + 8*(r>>2) + 4*h2;
    int c = nt*32 + col;
    if (m < NP && c < NP)
      out[(size_t)m*NP + c] = alpha*(a1[r]+a2[r]+a3[r]) + cAdd + (m==c ? diagAdd : 0.f);
  }
}

// ---------------- NS init: ninf bound, X0 = c*I, Y0 = c*A (Y tracks A@X) ----------------
__global__ __launch_bounds__(256) void k_nsinit2(
    const float* __restrict__ A, float* __restrict__ X, float* __restrict__ Y) {
  int b = blockIdx.x, t = threadIdx.x;
  const float* Ab = A + (size_t)b*MAT;
  __shared__ float sm[256];
  float lm = 0.f;
  if (t < NP) {
    float s = 0.f;
    for (int j = 0; j < NP; ++j) {
      float v = Ab[t*NP + j];
      if (j == t) v -= 1.f;
      s += fabsf(v);
    }
    lm = s;
  }
  sm[t] = lm; __syncthreads();
  for (int o = 128; o; o >>= 1) { if (t < o) sm[t] = fmaxf(sm[t], sm[t+o]); __syncthreads(); }
  float cc = 2.f / (2.f + sm[0]);
  float* Xb = X + (size_t)b*MAT;
  float* Yb = Y + (size_t)b*MAT;
  for (int idx = t; idx < MAT; idx += 256) {
    Xb[idx] = (idx % (NP+1) == 0) ? cc : 0.f;
    Yb[idx] = cc * Ab[idx];
  }
}

// ---------------- NS iter: z<32: Xn=2X-X@Y ; z>=32: Yn=2Y-Y@Y ----------------
__global__ __launch_bounds__(256) void k_ns(
    const float* __restrict__ X, const float* __restrict__ Y,
    float* __restrict__ Xn, float* __restrict__ Yn) {
  int zz = blockIdx.z; int b = zz & 31; bool hy = (zz >= 32);
  const float* Lb = (hy ? Y : X) + (size_t)b*MAT;
  const float* Rb = Y + (size_t)b*MAT;
  float* Ob = (hy ? Yn : Xn) + (size_t)b*MAT;
  int c0 = blockIdx.x * 64, r0 = blockIdx.y * 64;
  __shared__ __align__(16) float Ls[16][68];
  __shared__ __align__(16) float Rs[16][64];
  int t = threadIdx.x, tx = t & 15, ty = t >> 4;
  int alr = t >> 2, alc = (t & 3) << 2;
  int blr = t >> 4, blc = (t & 15) << 2;
  float acc[4][4] = {};
  int lrow = min(r0 + alr, NP-1);
  for (int k0 = 0; k0 < NP; k0 += 16) {
    float4 lv = {0.f,0.f,0.f,0.f};
    if (k0 + alc < NP) lv = *reinterpret_cast<const float4*>(&Lb[(size_t)lrow*NP + k0 + alc]);
    float4 rv = {0.f,0.f,0.f,0.f};
    if (k0 + blr < NP) rv = *reinterpret_cast<const float4*>(&Rb[(size_t)(k0+blr)*NP + c0 + blc]);
    Ls[alc+0][alr] = lv.x; Ls[alc+1][alr] = lv.y;
    Ls[alc+2][alr] = lv.z; Ls[alc+3][alr] = lv.w;
    *reinterpret_cast<float4*>(&Rs[blr][blc]) = rv;
    __syncthreads();
    #pragma unroll
    for (int kt = 0; kt < 16; ++kt) {
      float a4[4], b4[4];
      *reinterpret_cast<float4*>(a4) = *reinterpret_cast<const float4*>(&Ls[kt][ty<<2]);
      *reinterpret_cast<float4*>(b4) = *reinterpret_cast<const float4*>(&Rs[kt][tx<<2]);
      #pragma unroll
      for (int i = 0; i < 4; ++i)
        #pragma unroll
        for (int j = 0; j < 4; ++j) acc[i][j] += a4[i]*b4[j];
    }
    __syncthreads();
  }
  #pragma unroll
  for (int i = 0; i < 4; ++i) {
    int r = r0 + (ty<<2) + i; if (r >= NP) continue;
    #pragma unroll
    for (int j = 0; j < 4; ++j) {
      int c = c0 + (tx<<2) + j; if (c >= NP) continue;
      Ob[(size_t)r*NP + c] = 2.f*Lb[(size_t)r*NP + c] - acc[i][j];
    }
  }
}

// ---------------- Minv -> bf16 hi/lo split, pre-swizzled into MFMA A-fragment order ----
__global__ __launch_bounds__(256) void k_swz(
    const float* __restrict__ Minv,
    unsigned short* __restrict__ Ahi, unsigned short* __restrict__ Alo) {
  int bid = blockIdx.x;          // 32*7
  int b = bid & 31, mt = bid >> 5;
  int t = threadIdx.x;
  int l = t & 63, jp = (t >> 6) * 2;
  int m = mt*32 + (l & 31);
  const float* Mb = Minv + (size_t)b*MAT;
  size_t obase = ((size_t)(b*7 + mt)*13)*512;
  for (int ks = 0; ks < 13; ++ks) {
    #pragma unroll
    for (int jo = 0; jo < 2; ++jo) {
      int j = jp + jo;
      int k = ks*16 + (l>>5)*8 + j;
      float v = (m < NP && k < NP) ? Mb[(size_t)m*NP + k] : 0.f;
      unsigned short hh = f2bf(v);
      unsigned short ll = f2bf(v - bf2f(hh));
      size_t idx = obase + (size_t)ks*512 + l*8 + j;
      Ahi[idx] = hh; Alo[idx] = ll;
    }
  }
}

// ---------------- fused 50-iter ADMM: bf16-split MFMA ----------------
__global__ __launch_bounds__(448) void k_admm7(
    const unsigned short* __restrict__ Ahi, const unsigned short* __restrict__ Alo,
    const float* __restrict__ P, float* __restrict__ w) {
  int bid = blockIdx.x;
  int b = bid & 31, tt = bid >> 5;
  int t = threadIdx.x;
  int wv = t >> 6;
  int l = t & 63;
  int n_l = l & 31, h = l >> 5;
  int n = tt*32 + n_l;
  int mt = wv;

  __shared__ __align__(16) unsigned short Bhi[26*32*8];
  __shared__ __align__(16) unsigned short Blo[26*32*8];
  __shared__ float ssum[7][32];

  float z[16], u[16], pr[16];
  int ngc = min(n, NP-1);
  const float* prow = P + ((size_t)b*NP + ngc)*NP;
  #pragma unroll
  for (int r = 0; r < 16; ++r) {
    int m = mt*32 + (r&3) + 8*(r>>2) + 4*h;
    pr[r] = prow[min(m, NP-1)];
    z[r] = 0.f; u[r] = 0.f;
  }
  #pragma unroll
  for (int r = 0; r < 16; ++r) {
    int m = mt*32 + (r&3) + 8*(r>>2) + 4*h;
    float rhs = -pr[r];
    unsigned short hh = f2bf(rhs);
    unsigned short ll = f2bf(rhs - bf2f(hh));
    int idx = ((m >> 3)*32 + n_l)*8 + (m & 7);
    Bhi[idx] = hh; Blo[idx] = ll;
  }
  __syncthreads();

  const unsigned short* ah_base = Ahi + ((size_t)(b*7 + mt)*13)*512 + l*8;
  const unsigned short* al_base = Alo + ((size_t)(b*7 + mt)*13)*512 + l*8;
  int boff = (h*32 + n_l)*8;

  for (int it = 0; it < 50; ++it) {
    f32x16 acc1, acc2, acc3;
    #pragma unroll
    for (int i = 0; i < 16; ++i) { acc1[i] = 0.f; acc2[i] = 0.f; acc3[i] = 0.f; }
    #pragma unroll
    for (int ks = 0; ks < 13; ++ks) {
      short8 ah = *reinterpret_cast<const short8*>(ah_base + (size_t)ks*512);
      short8 al = *reinterpret_cast<const short8*>(al_base + (size_t)ks*512);
      short8 bh = *reinterpret_cast<const short8*>(&Bhi[ks*512 + boff]);
      short8 bl = *reinterpret_cast<const short8*>(&Blo[ks*512 + boff]);
      acc1 = __builtin_amdgcn_mfma_f32_32x32x16_bf16(ah, bh, acc1, 0, 0, 0);
      acc2 = __builtin_amdgcn_mfma_f32_32x32x16_bf16(ah, bl, acc2, 0, 0, 0);
      acc3 = __builtin_amdgcn_mfma_f32_32x32x16_bf16(al, bh, acc3, 0, 0, 0);
    }
    __syncthreads();
    #pragma unroll
    for (int r = 0; r < 16; ++r) {
      int m = mt*32 + (r&3) + 8*(r>>2) + 4*h;
      float x = acc1[r] + acc2[r] + acc3[r];
      float xpu = x + u[r];
      float zz = fminf(fmaxf(xpu, 0.f), 1.f);
      u[r] = xpu - zz;
      z[r] = zz;
      float rhs = zz - u[r] - pr[r];
      unsigned short hh = f2bf(rhs);
      unsigned short ll = f2bf(rhs - bf2f(hh));
      int idx = ((m >> 3)*32 + n_l)*8 + (m & 7);
      Bhi[idx] = hh; Blo[idx] = ll;
    }
    __syncthreads();
  }

  float s = 0.f;
  #pragma unroll
  for (int r = 0; r < 16; ++r) {
    int m = mt*32 + (r&3) + 8*(r>>2) + 4*h;
    if (m < NP) s += z[r];
  }
  s += __shfl_xor(s, 32, 64);
  if (l < 32) ssum[wv][n_l] = s;
  __syncthreads();
  float stot = 0.f;
  #pragma unroll
  for (int q = 0; q < 7; ++q) stot += ssum[q][n_l];
  float inv = (n < NP) ? 1.f/(stot + 1e-10f) : 0.f;
  #pragma unroll
  for (int r = 0; r < 16; ++r) {
    float c = z[r] * inv * (1.f/196.f);
    #pragma unroll
    for (int o = 16; o; o >>= 1) c += __shfl_xor(c, o, 64);
    if (n_l == 0) {
      int m = mt*32 + (r&3) + 8*(r>>2) + 4*h;
      if (m < NP) atomicAdd(&w[b*NP + m], c);
    }
  }
}

// ---------------- pooled + LN -> pl_g[b][512] ----------------
__global__ __launch_bounds__(256) void k_pool(
    const float* __restrict__ w, const float* __restrict__ V,
    const float* __restrict__ g, const float* __restrict__ be,
    float* __restrict__ pl_g) {
  int b = blockIdx.x, t = threadIdx.x;
  __shared__ float ws_[NP];
  __shared__ float rb[8];
  if (t < NP) ws_[t] = w[b*NP + t];
  __syncthreads();
  const float* Vb = V + (size_t)b*NP*512;
  float a0 = 0.f, a1 = 0.f;
  #pragma unroll 4
  for (int m = 0; m < NP; ++m) {
    float wm = ws_[m];
    a0 = fmaf(wm, Vb[(size_t)m*512 + t], a0);
    a1 = fmaf(wm, Vb[(size_t)m*512 + 256 + t], a1);
  }
  float s = a0+a1, ss = a0*a0+a1*a1;
  for (int o = 32; o; o >>= 1) { s += __shfl_down(s,o); ss += __shfl_down(ss,o); }
  if ((t&63)==0) { rb[t>>6]=s; rb[4+(t>>6)]=ss; }
  __syncthreads();
  float S = rb[0]+rb[1]+rb[2]+rb[3], SS = rb[4]+rb[5]+rb[6]+rb[7];
  float mu = S*(1.f/512.f), var = SS*(1.f/512.f)-mu*mu, inv = rsqrtf(var+1e-5f);
  pl_g[(size_t)b*512 + t]       = (a0-mu)*inv*g[t] + be[t];
  pl_g[(size_t)b*512 + 256 + t] = (a1-mu)*inv*g[t+256] + be[t+256];
}

// ---------------- head GEMM: 256 blocks (8 col-groups x 32 batches), k-split 4 ----------
__global__ __launch_bounds__(512) void k_head(
    const float* __restrict__ pl_g, const float* __restrict__ Wm,
    const float* __restrict__ bm, float* __restrict__ logits) {
  int cg = blockIdx.x, b = blockIdx.y;
  int t = threadIdx.x;
  int c0 = cg * 125;
  __shared__ float pl[512];
  __shared__ float part[4][128];
  pl[t] = pl_g[(size_t)b*512 + t];
  __syncthreads();
  int kk = t >> 7, cc = t & 127;
  float a = 0.f;
  if (cc < 125) {
    int c = c0 + cc;
    const float* wp = Wm + (size_t)(kk*128)*NC + c;
    #pragma unroll 8
    for (int k = 0; k < 128; ++k) a = fmaf(pl[kk*128 + k], wp[(size_t)k*NC], a);
  }
  part[kk][cc] = a;
  __syncthreads();
  if (t < 125) {
    float lg = part[0][t] + part[1][t] + part[2][t] + part[3][t] + bm[c0 + t];
    logits[(size_t)b*NC + c0 + t] = lg;
  }
}

// ---------------- softmax over 1000 ----------------
__global__ __launch_bounds__(256) void k_soft(
    const float* __restrict__ logits, float* __restrict__ out) {
  int b = blockIdx.x, t = threadIdx.x;
  __shared__ float rb[8];
  float lg[4];
  #pragma unroll
  for (int q = 0; q < 4; ++q) {
    int c = t + (q<<8);
    lg[q] = (c < NC) ? logits[(size_t)b*NC + c] : -1e30f;
  }
  float mx = fmaxf(fmaxf(lg[0],lg[1]), fmaxf(lg[2],lg[3]));
  for (int o = 32; o; o >>= 1) mx = fmaxf(mx, __shfl_down(mx,o));
  if ((t&63)==0) rb[t>>6] = mx;
  __syncthreads();
  float MX = fmaxf(fmaxf(rb[0],rb[1]), fmaxf(rb[2],rb[3]));
  float es = 0.f, ev[4];
  #pragma unroll
  for (int q = 0; q < 4; ++q) {
    int c = t + (q<<8);
    ev[q] = (c < NC) ? __expf(lg[q]-MX) : 0.f;
    es += ev[q];
  }
  for (int o = 32; o; o >>= 1) es += __shfl_down(es,o);
  __syncthreads();
  if ((t&63)==0) rb[4+(t>>6)] = es;
  __syncthreads();
  float SUM = rb[4]+rb[5]+rb[6]+rb[7];
  float rinv = 1.f/SUM;
  #pragma unroll
  for (int q = 0; q < 4; ++q) {
    int c = t + (q<<8);
    if (c < NC) out[(size_t)b*NC + c] = ev[q]*rinv;
  }
}

extern "C" void kernel_launch(void* const* d_in, const int* in_sizes, int n_in,
                              void* d_out, int out_size, void* d_ws, size_t ws_size,
                              hipStream_t stream) {
  const float* img = (const float*)d_in[0];
  const float* lpg = (const float*)d_in[1];
  const float* lpb = (const float*)d_in[2];
  const float* wqw = (const float*)d_in[3];
  const float* wqb = (const float*)d_in[4];
  const float* lqg = (const float*)d_in[5];
  const float* lqb = (const float*)d_in[6];
  const float* wvw = (const float*)d_in[7];
  const float* wvb = (const float*)d_in[8];
  const float* lvg = (const float*)d_in[9];
  const float* lvb = (const float*)d_in[10];
  const float* pos = (const float*)d_in[11];
  const float* mlg = (const float*)d_in[12];
  const float* mlb = (const float*)d_in[13];
  const float* mw  = (const float*)d_in[14];
  const float* mb  = (const float*)d_in[15];
  float* outp = (float*)d_out;

  float* ws = (float*)d_ws;
  size_t off = 0;
  float* q  = ws + off;      off += (size_t)B_*NP*DM;
  float* v  = ws + off;      off += (size_t)B_*NP*DM;
  size_t matp = (size_t)B_*MAT + 256;
  float* A  = ws + off;      off += matp;
  float* p  = ws + off;      off += matp;
  float* Xa = ws + off;      off += matp;
  float* Xb = ws + off;      off += matp;
  float* Ya = ws + off;      off += matp;
  float* Yb = A;                            // alias: A dead after k_nsinit2
  float* w  = ws + off;      off += (size_t)B_*NP;
  float* pl_g = ws + off;    off += (size_t)B_*DM;
  float* logits = ws + off;  off += (size_t)B_*NC;
  off = (off + 3) & ~(size_t)3;             // 16B align for short8 loads
  size_t swzE = (size_t)B_*7*13*512;        // Minv frag ushorts per component
  unsigned short* Ahi = (unsigned short*)(ws + off); off += swzE/2;
  unsigned short* Alo = (unsigned short*)(ws + off); off += swzE/2;
  size_t xfE = (size_t)196*48*512;          // X frag ushorts per component
  unsigned short* Xfh = (unsigned short*)(ws + off); off += xfE/2;
  unsigned short* Xfl = (unsigned short*)(ws + off); off += xfE/2;
  size_t wfE = (size_t)16*48*512;           // W frag ushorts per component
  unsigned short* Wqh = (unsigned short*)(ws + off); off += wfE/2;
  unsigned short* Wql = (unsigned short*)(ws + off); off += wfE/2;
  unsigned short* Wvh = (unsigned short*)(ws + off); off += wfE/2;
  unsigned short* Wvl = (unsigned short*)(ws + off); off += wfE/2;
  size_t qvfE = (size_t)B_*2*7*32*512;      // q/v Gram frag ushorts per component
  unsigned short* Fh = (unsigned short*)(ws + off); off += qvfE/2;
  unsigned short* Fl = (unsigned short*)(ws + off); off += qvfE/2;
  if (ws_size < off * sizeof(float)) return;

  k_wswz<<<dim3(768), 256, 0, stream>>>(wqw, Wqh, Wql);
  k_wswz<<<dim3(768), 256, 0, stream>>>(wvw, Wvh, Wvl);
  k_patchify<<<dim3(B_*NP), 256, 0, stream>>>(img, lpg, lpb, pos, Xfh, Xfl);
  k_qv_mfma<<<dim3(392), 256, 0, stream>>>(Xfh, Xfl, Wqh, Wql, Wvh, Wvl,
                                           wqb, wvb, q, v);
  k_ln2<<<dim3(2*B_*NP), 256, 0, stream>>>(q, v, lqg, lqb, lvg, lvb, Fh, Fl);
  k_gram_mfma<<<dim3(49, 64), 64, 0, stream>>>(Fh, Fl, A, p);
  k_nsinit2<<<dim3(B_), 256, 0, stream>>>(A, Xa, Ya);
  k_ns<<<dim3(4,4,64), 256, 0, stream>>>(Xa, Ya, Xb, Yb);
  k_ns<<<dim3(4,4,64), 256, 0, stream>>>(Xb, Yb, Xa, Ya);
  k_ns<<<dim3(4,4,64), 256, 0, stream>>>(Xa, Ya, Xb, Yb);
  k_swz<<<dim3(B_*7), 256, 0, stream>>>(Xb, Ahi, Alo);
  (void)hipMemsetAsync(w, 0, (size_t)B_*NP*sizeof(float), stream);
  k_admm7<<<dim3(7*B_), 448, 0, stream>>>(Ahi, Alo, p, w);
  k_pool<<<dim3(B_), 256, 0, stream>>>(w, v, mlg, mlb, pl_g);
  k_head<<<dim3(8, B_), 512, 0, stream>>>(pl_g, mw, mb, logits);
  k_soft<<<dim3(B_), 256, 0, stream>>>(logits, outp);
}